// Round 6
// baseline (1836.150 us; speedup 1.0000x reference)
//
#include <hip/hip_runtime.h>
#include <math.h>

#define BATCH 16384
#define NSMAX 8
#define LOG2PI_F 1.8378770664093453f
#define LOG4_F 1.3862943611198906f

typedef _Float16 v8h __attribute__((ext_vector_type(8)));
typedef float    v4f __attribute__((ext_vector_type(4)));
typedef float    v2f __attribute__((ext_vector_type(2)));

#define MFMA16(A,B,C) __builtin_amdgcn_mfma_f32_16x16x32_f16(A,B,C,0,0,0)

__device__ __forceinline__ float bcast(float v, int l) {
    return __uint_as_float(__builtin_amdgcn_readlane(__float_as_uint(v), (unsigned)l));
}
__device__ __forceinline__ float fsigm(float v){ return 1.f/(1.f + __expf(-v)); }
__device__ __forceinline__ float ftanh(float v){ return 1.f - 2.f/(__expf(2.f*v)+1.f); }
__device__ __forceinline__ float fsp(float v){ return fmaxf(v,0.f) + __logf(1.f + __expf(-fabsf(v))); }

__device__ __forceinline__ v8h ld8(const float* p){
    v4f a = *(const v4f*)p; v4f b = *(const v4f*)(p+4);
    v8h r;
    r[0]=(_Float16)a[0]; r[1]=(_Float16)a[1]; r[2]=(_Float16)a[2]; r[3]=(_Float16)a[3];
    r[4]=(_Float16)b[0]; r[5]=(_Float16)b[1]; r[6]=(_Float16)b[2]; r[7]=(_Float16)b[3];
    return r;
}
__device__ __forceinline__ v8h ld8lo(const float* p){
    v4f a = *(const v4f*)p; v4f b = *(const v4f*)(p+4);
    v8h r;
    #pragma unroll
    for (int j=0;j<4;++j){ _Float16 h=(_Float16)a[j]; r[j]=(_Float16)(a[j]-(float)h); }
    #pragma unroll
    for (int j=0;j<4;++j){ _Float16 h=(_Float16)b[j]; r[4+j]=(_Float16)(b[j]-(float)h); }
    return r;
}
__device__ __forceinline__ v8h ld8s(const float* p, int stride){
    v8h r;
    #pragma unroll
    for (int j=0;j<8;++j) r[j] = (_Float16)p[j*stride];
    return r;
}
__device__ __forceinline__ v8h ld8slo(const float* p, int stride){
    v8h r;
    #pragma unroll
    for (int j=0;j<8;++j){ float v=p[j*stride]; _Float16 h=(_Float16)v; r[j]=(_Float16)(v-(float)h); }
    return r;
}
__device__ __forceinline__ unsigned packh2(float a, float b){
    unsigned short au = __builtin_bit_cast(unsigned short, (_Float16)a);
    unsigned short bu = __builtin_bit_cast(unsigned short, (_Float16)b);
    return (unsigned)au | ((unsigned)bu<<16);
}
__device__ __forceinline__ float unpk_lo(unsigned p){
    return (float)__builtin_bit_cast(_Float16,(unsigned short)(p&0xffff));
}
__device__ __forceinline__ float unpk_hi(unsigned p){
    return (float)__builtin_bit_cast(_Float16,(unsigned short)(p>>16));
}

// ---------------------------------------------------------------------------
// K0: MLP -> z0 (fp32 scalar, proven)
// ---------------------------------------------------------------------------
__global__ __launch_bounds__(512) void k_mlp(
    const float* __restrict__ visual, const float* __restrict__ vel,
    const float* __restrict__ tl, const float* __restrict__ tls,
    const float* __restrict__ Wm1, const float* __restrict__ bm1,
    const float* __restrict__ Wm2, const float* __restrict__ bm2,
    const float* __restrict__ Wm3, const float* __restrict__ bm3,
    float* __restrict__ z0ws)
{
    __shared__ float smem[9600];
    const int tid  = threadIdx.x;
    const int lane = tid & 63;
    const int w    = tid >> 6;
    const int b    = blockIdx.x * 8 + w;
    for (int i = tid; i < 8512; i += 512) smem[i] = Wm1[i];
    float* sfeat = smem + 8512 + w * 136;
    sfeat[lane]      = visual[b*128 + lane];
    sfeat[64 + lane] = visual[b*128 + 64 + lane];
    if (lane < 3)  sfeat[128 + lane] = vel[b*3 + lane];
    if (lane == 3) sfeat[131] = tl[b];
    if (lane == 4) sfeat[132] = tls[b];
    __syncthreads();
    float acc = bm1[lane];
    for (int f = 0; f < 133; ++f) acc = fmaf(smem[f*64 + lane], sfeat[f], acc);
    float z1 = fmaxf(acc, 0.f);
    __syncthreads();
    for (int i = tid; i < 4096; i += 512) smem[i] = Wm2[i];
    __syncthreads();
    acc = bm2[lane];
    #pragma unroll 8
    for (int kk = 0; kk < 64; ++kk) acc = fmaf(smem[kk*64 + lane], bcast(z1, kk), acc);
    float z2 = fmaxf(acc, 0.f);
    __syncthreads();
    for (int i = tid; i < 4096; i += 512) smem[i] = Wm3[i];
    __syncthreads();
    acc = bm3[lane];
    #pragma unroll 8
    for (int kk = 0; kk < 64; ++kk) acc = fmaf(smem[kk*64 + lane], bcast(z2, kk), acc);
    z0ws[(size_t)b*64 + lane] = fmaxf(acc, 0.f);
}

// ---------------------------------------------------------------------------
// K1: MFMA flow. 2 waves/block, wave = 16 elements, grid 512, 2 blk/CU.
// ALL GRU weight frags in LDS: gruHi permanent; regB phase-swapped
// (gruLo during fwd, whhT during bwd). Only Wl1-family frags in registers.
// fwd = 6-term split (R5-exact); bwd gate recompute = 2-term (hi weights).
// ---------------------------------------------------------------------------
__global__ __launch_bounds__(128, 1) void k_adam(
    const float* __restrict__ goal, const float* __restrict__ bs,
    const float* __restrict__ wih, const float* __restrict__ whh,
    const float* __restrict__ bih, const float* __restrict__ bhh,
    const float* __restrict__ Wl1, const float* __restrict__ bl1,
    const float* __restrict__ Wl2, const float* __restrict__ bl2,
    const int*  __restrict__ nsp, const float* __restrict__ z0ws,
    float* __restrict__ traj, float* __restrict__ parts,
    _Float16* __restrict__ ckpt)
{
    __shared__ _Float16 gruHi[12288];     // hi(whh) frag-ordered, f=T*2+K, 24KB
    __shared__ _Float16 regB [12288];     // swap: gruLo (fwd) / whhT (bwd), 24KB
    __shared__ _Float16 stageL[2][3200];  // per-wave stage, stride 200 halfs
    __shared__ float    xsx[2][256];      // per-wave x / xbar

    const int tid  = threadIdx.x;
    const int w    = tid >> 6;
    const int ln   = tid & 63;
    const int col  = ln & 15;
    const int quad = ln >> 4;
    const int b0   = blockIdx.x*32 + w*16;
    _Float16* sw = stageL[w];
    float*    xw = xsx[w];

    // block-wide fill helpers
    auto fillHi = [&](){
        for (int i = tid; i < 24*64; i += 128){
            int f = i>>6, l = i&63, lc = l&15, lq = l>>4;
            int T = f>>1, K = f&1;
            *(v8h*)(gruHi + f*512 + l*8) = ld8(whh + (lc+16*T)*64 + 32*K + lq*8);
        }
    };
    auto fillLo = [&](){
        for (int i = tid; i < 24*64; i += 128){
            int f = i>>6, l = i&63, lc = l&15, lq = l>>4;
            int T = f>>1, K = f&1;
            *(v8h*)(regB + f*512 + l*8) = ld8lo(whh + (lc+16*T)*64 + 32*K + lq*8);
        }
    };
    auto fillT = [&](){
        for (int i = tid; i < 24*64; i += 128){
            int f = i>>6, l = i&63, lc = l&15, lq = l>>4;
            int Tz = f/6, kc = f - Tz*6;
            *(v8h*)(regB + f*512 + l*8) = ld8s(whh + (kc*32+lq*8)*64 + lc + 16*Tz, 64);
        }
    };
    fillHi();

    // ---- register weights (Wl1 family only) ----
    v8h w1h[2][2], w1l[2][2];
    #pragma unroll
    for (int T=0;T<2;++T){
        int n = col + 16*T;
        w1h[T][0] = ld8s  (Wl1 + (     quad*8)*32 + n, 32);
        w1h[T][1] = ld8s  (Wl1 + (32 + quad*8)*32 + n, 32);
        w1l[T][0] = ld8slo(Wl1 + (     quad*8)*32 + n, 32);
        w1l[T][1] = ld8slo(Wl1 + (32 + quad*8)*32 + n, 32);
    }
    v8h awl1[4];
    #pragma unroll
    for (int Tz=0;Tz<4;++Tz)
        awl1[Tz] = ld8(Wl1 + (col+16*Tz)*32 + quad*8);

    float wi0[12], wi1[12];
    #pragma unroll
    for (int T=0;T<12;++T){
        int c = col + 16*T;
        wi0[T] = wih[c*2]; wi1[T] = wih[c*2+1];
    }
    float bsum[8], bn_i[4], bn_h[4];
    #pragma unroll
    for (int T=0;T<8;++T) bsum[T] = bih[col+16*T] + bhh[col+16*T];
    #pragma unroll
    for (int T=0;T<4;++T){
        bn_i[T] = bih[128+col+16*T];
        bn_h[T] = bhh[128+col+16*T];
    }
    float w2[2][4], bl1v[2];
    #pragma unroll
    for (int T=0;T<2;++T){
        int i5 = col + 16*T;
        bl1v[T] = bl1[i5];
        #pragma unroll
        for (int j=0;j<4;++j) w2[T][j] = Wl2[i5*4+j];
    }
    float b2[4] = {bl2[0], bl2[1], bl2[2], bl2[3]};

    float xa0 = bs[2*quad], xa1 = bs[2*quad+1];
    xw[col*16 + 2*quad]   = xa0;
    xw[col*16 + 2*quad+1] = xa1;
    float am0=0,am1=0,av0=0,av1=0,pb1=1.f,pb2=1.f;

    int ns = *nsp; if (ns > NSMAX) ns = NSMAX;

    unsigned rnp[4][4];
    float ug[4][4], ghs[4][4], aa[2][4];
    float s0v[4], s1v[4], c0v[4], c1v[4];
    float zc[4][4];

    // GRU cell + heads. split=true: fwd 6-term (gruHi + regB=gruLo).
    // split=false: bwd 2-term (gruHi only; regB holds whhT then).
    auto cell = [&](bool split, const float (&yp0)[4], const float (&yp1)[4],
                    const float (&zprev)[4][4]){
        v8h ah0 = *(const v8h*)(sw + col*200 +      quad*8);
        v8h ah1 = *(const v8h*)(sw + col*200 + 32 + quad*8);
        v8h al0, al1;
        if (split){
            al0 = *(const v8h*)(sw + col*200 + 64 + quad*8);
            al1 = *(const v8h*)(sw + col*200 + 96 + quad*8);
        }
        float znew[4][4];
        #pragma unroll
        for (int Tz=0;Tz<4;++Tz){
            v4f g3[3];
            #pragma unroll
            for (int gg=0; gg<3; ++gg){
                int tg = Tz + 4*gg;
                v8h h0 = *(const v8h*)(gruHi + (tg*2  )*512 + ln*8);
                v8h h1 = *(const v8h*)(gruHi + (tg*2+1)*512 + ln*8);
                v4f acc = {0,0,0,0};
                if (split){
                    v8h l0 = *(const v8h*)(regB + (tg*2  )*512 + ln*8);
                    v8h l1 = *(const v8h*)(regB + (tg*2+1)*512 + ln*8);
                    acc = MFMA16(ah0, l0, acc);
                    acc = MFMA16(ah1, l1, acc);
                    acc = MFMA16(al0, h0, acc);
                    acc = MFMA16(al1, h1, acc);
                }
                acc = MFMA16(ah0, h0, acc);
                acc = MFMA16(ah1, h1, acc);
                g3[gg] = acc;
            }
            #pragma unroll
            for (int r=0;r<4;++r){
                float pr = g3[0][r] + wi0[Tz]*yp0[r]   + wi1[Tz]*yp1[r]   + bsum[Tz];
                float pu = g3[1][r] + wi0[Tz+4]*yp0[r] + wi1[Tz+4]*yp1[r] + bsum[Tz+4];
                float gh = g3[2][r] + bn_h[Tz];
                float gi = wi0[Tz+8]*yp0[r] + wi1[Tz+8]*yp1[r] + bn_i[Tz];
                float R = fsigm(pr), U = fsigm(pu);
                float N = ftanh(gi + R*gh);
                if (!split){ rnp[Tz][r]=packh2(R,N); ug[Tz][r]=U; ghs[Tz][r]=gh; }
                znew[Tz][r] = (1.f-U)*N + U*zprev[Tz][r];
            }
        }
        if (split){
            #pragma unroll
            for (int Tz=0;Tz<4;++Tz)
                #pragma unroll
                for (int r=0;r<4;++r){
                    float v = znew[Tz][r];
                    zc[Tz][r] = v;
                    _Float16 h = (_Float16)v;
                    int o = (quad*4+r)*200 + col + 16*Tz;
                    sw[o] = h; sw[o+64] = (_Float16)(v-(float)h);
                }
        } else {
            #pragma unroll
            for (int Tz=0;Tz<4;++Tz)
                #pragma unroll
                for (int r=0;r<4;++r)
                    sw[(quad*4+r)*200 + col + 16*Tz] = (_Float16)znew[Tz][r];
        }
        v8h bh0 = *(const v8h*)(sw + col*200 +      quad*8);
        v8h bh1 = *(const v8h*)(sw + col*200 + 32 + quad*8);
        v8h bl0, blf;
        if (split){
            bl0 = *(const v8h*)(sw + col*200 + 64 + quad*8);
            blf = *(const v8h*)(sw + col*200 + 96 + quad*8);
        }
        #pragma unroll
        for (int T=0;T<2;++T){
            v4f acc = {0.f,0.f,0.f,0.f};
            acc = MFMA16(bh0, w1l[T][0], acc);
            acc = MFMA16(bh1, w1l[T][1], acc);
            if (split){
                acc = MFMA16(bl0, w1h[T][0], acc);
                acc = MFMA16(blf, w1h[T][1], acc);
            }
            acc = MFMA16(bh0, w1h[T][0], acc);
            acc = MFMA16(bh1, w1h[T][1], acc);
            #pragma unroll
            for (int r=0;r<4;++r) aa[T][r] = fmaxf(acc[r] + bl1v[T], 0.f);
        }
        #pragma unroll
        for (int r=0;r<4;++r){
            float q2 = aa[0][r]*w2[0][2] + aa[1][r]*w2[1][2];
            float q3 = aa[0][r]*w2[0][3] + aa[1][r]*w2[1][3];
            float q0 = 0.f, q1 = 0.f;
            if (split){
                q0 = aa[0][r]*w2[0][0] + aa[1][r]*w2[1][0];
                q1 = aa[0][r]*w2[0][1] + aa[1][r]*w2[1][1];
            }
            #pragma unroll
            for (int m=1;m<16;m<<=1){
                q2 += __shfl_xor(q2,m); q3 += __shfl_xor(q3,m);
                if (split){ q0 += __shfl_xor(q0,m); q1 += __shfl_xor(q1,m); }
            }
            if (split){ c0v[r] = q0 + b2[0]; c1v[r] = q1 + b2[1]; }
            s0v[r] = fsp(q2 + b2[2]) + 0.001f;
            s1v[r] = fsp(q3 + b2[3]) + 0.001f;
        }
    };

    const int crow = ln >> 2;
    const int ccol = (ln & 3) * 16;

    for (int s=0; s<ns; ++s){
        __syncthreads();            // prior-phase regB reads done
        fillLo();                   // regB = gruLo
        __syncthreads();
        // reset z to z0 (stage split)
        #pragma unroll
        for (int Tz=0;Tz<4;++Tz)
            #pragma unroll
            for (int r=0;r<4;++r){
                float v = z0ws[(size_t)(b0+quad*4+r)*64 + col + 16*Tz];
                zc[Tz][r] = v;
                _Float16 h = (_Float16)v;
                int o = (quad*4+r)*200 + col + 16*Tz;
                sw[o] = h; sw[o+64] = (_Float16)(v-(float)h);
            }
        // ---------- forward ----------
        float y0[4]={0,0,0,0}, y1[4]={0,0,0,0};
        float sumls[4]={0,0,0,0}, sumx2[4]={0,0,0,0};
        #pragma unroll
        for (int t=0;t<4;++t){
            float zprev[4][4];
            #pragma unroll
            for (int Tz=0;Tz<4;++Tz)
                #pragma unroll
                for (int r=0;r<4;++r) zprev[Tz][r] = zc[Tz][r];
            cell(true, y0, y1, zprev);
            #pragma unroll
            for (int r=0;r<4;++r){
                v2f xv = *(const v2f*)(&xw[(quad*4+r)*16 + 2*t]);
                sumx2[r] += xv[0]*xv[0] + xv[1]*xv[1];
                y0[r] += c0v[r] + s0v[r]*xv[0];
                y1[r] += c1v[r] + s1v[r]*xv[1];
                int o = (quad*4+r)*200 + 192 + 2*t;
                sw[o] = (_Float16)y0[r]; sw[o+1] = (_Float16)y1[r];
                sumls[r] += __logf(s0v[r]) + __logf(s1v[r]);
            }
            if (t<3){
                v8h z1 = *(const v8h*)(sw + crow*200 + ccol);
                v8h z2 = *(const v8h*)(sw + crow*200 + ccol + 8);
                _Float16* gp = ckpt + ((size_t)t*BATCH + (b0+crow))*64 + ccol;
                *(v8h*)gp = z1; *(v8h*)(gp+8) = z2;
            }
        }
        // ---------- loss + y-grad ----------
        float cel[4], yb0[4], yb1[4];
        #pragma unroll
        for (int r=0;r<4;++r){
            const float* gpt = goal + (size_t)(b0+quad*4+r)*8;
            v4f ga = *(const v4f*)gpt; v4f gb = *(const v4f*)(gpt+4);
            float c0_ = -0.5f*((y0[r]-ga[0])*(y0[r]-ga[0]) + (y1[r]-ga[1])*(y1[r]-ga[1])) - LOG2PI_F;
            float c1_ = -0.5f*((y0[r]-ga[2])*(y0[r]-ga[2]) + (y1[r]-ga[3])*(y1[r]-ga[3])) - LOG2PI_F;
            float c2_ = -0.5f*((y0[r]-gb[0])*(y0[r]-gb[0]) + (y1[r]-gb[1])*(y1[r]-gb[1])) - LOG2PI_F;
            float c3_ = -0.5f*((y0[r]-gb[2])*(y0[r]-gb[2]) + (y1[r]-gb[3])*(y1[r]-gb[3])) - LOG2PI_F;
            float mx = fmaxf(fmaxf(c0_,c1_), fmaxf(c2_,c3_));
            float e0 = __expf(c0_-mx), e1 = __expf(c1_-mx), e2 = __expf(c2_-mx), e3 = __expf(c3_-mx);
            float se = e0+e1+e2+e3;
            float lp = mx + __logf(se) - LOG4_F;
            cel[r] = -0.5f*sumx2[r] - 4.f*LOG2PI_F - sumls[r] + lp;
            float inv = 1.f/se;
            yb0[r] = inv*(e0*(ga[0]-y0[r]) + e1*(ga[2]-y0[r]) + e2*(gb[0]-y0[r]) + e3*(gb[2]-y0[r]));
            yb1[r] = inv*(e0*(ga[1]-y1[r]) + e1*(ga[3]-y1[r]) + e2*(gb[1]-y1[r]) + e3*(gb[3]-y1[r]));
        }
        float tsum = cel[0]+cel[1]+cel[2]+cel[3];
        tsum += __shfl_xor(tsum,16); tsum += __shfl_xor(tsum,32);
        if (ln==0) parts[s*1024 + blockIdx.x*2 + w] = tsum;

        __syncthreads();            // fwd regB reads done
        fillT();                    // regB = whhT
        __syncthreads();

        // ---------- backward ----------
        float zbN[4][4];
        #pragma unroll
        for (int Tz=0;Tz<4;++Tz){ zbN[Tz][0]=0;zbN[Tz][1]=0;zbN[Tz][2]=0;zbN[Tz][3]=0; }
        #pragma unroll
        for (int tt=0; tt<4; ++tt){
            const int t = 3-tt;
            float zcp[4][4];
            if (t > 0){
                const _Float16* gp = ckpt + ((size_t)(t-1)*BATCH + (b0+crow))*64 + ccol;
                v8h z1 = *(const v8h*)gp; v8h z2 = *(const v8h*)(gp+8);
                *(v8h*)(sw + crow*200 + ccol) = z1;
                *(v8h*)(sw + crow*200 + ccol + 8) = z2;
                #pragma unroll
                for (int Tz=0;Tz<4;++Tz)
                    #pragma unroll
                    for (int r=0;r<4;++r)
                        zcp[Tz][r] = (float)sw[(quad*4+r)*200 + col + 16*Tz];
            } else {
                #pragma unroll
                for (int Tz=0;Tz<4;++Tz)
                    #pragma unroll
                    for (int r=0;r<4;++r){
                        _Float16 h = (_Float16)z0ws[(size_t)(b0+quad*4+r)*64 + col + 16*Tz];
                        zcp[Tz][r] = (float)h;
                        sw[(quad*4+r)*200 + col + 16*Tz] = h;
                    }
            }
            float yp0[4], yp1[4];
            #pragma unroll
            for (int r=0;r<4;++r){
                if (t==0){ yp0[r]=0.f; yp1[r]=0.f; }
                else {
                    int o = (quad*4+r)*200 + 192 + 2*(t-1);
                    yp0[r] = (float)sw[o]; yp1[r] = (float)sw[o+1];
                }
            }
            cell(false, yp0, yp1, zcp);

            float l2[4], l3[4];
            #pragma unroll
            for (int r=0;r<4;++r){
                v2f xv = *(const v2f*)(&xw[(quad*4+r)*16 + 2*t]);
                float sb0 = yb0[r]*xv[0] - 1.f/s0v[r];
                float sb1 = yb1[r]*xv[1] - 1.f/s1v[r];
                float sg0 = 1.f - __expf(-(s0v[r]-0.001f));
                float sg1 = 1.f - __expf(-(s1v[r]-0.001f));
                l2[r] = sb0*sg0; l3[r] = sb1*sg1;
                v2f xb; xb[0] = yb0[r]*s0v[r] - xv[0]; xb[1] = yb1[r]*s1v[r] - xv[1];
                *(v2f*)(&xw[(quad*4+r)*16 + 8 + 2*t]) = xb;
            }
            #pragma unroll
            for (int T=0;T<2;++T)
                #pragma unroll
                for (int r=0;r<4;++r){
                    float ab = w2[T][0]*yb0[r] + w2[T][1]*yb1[r] + w2[T][2]*l2[r] + w2[T][3]*l3[r];
                    ab = (aa[T][r] > 0.f) ? ab : 0.f;
                    sw[(quad*4+r)*200 + 128 + col + 16*T] = (_Float16)ab;
                }
            v8h a_ab = *(const v8h*)(sw + col*200 + 128 + quad*8);
            float dzt[4][4];
            #pragma unroll
            for (int Tz=0;Tz<4;++Tz){
                v4f acc = { zbN[Tz][0], zbN[Tz][1], zbN[Tz][2], zbN[Tz][3] };
                acc = MFMA16(a_ab, awl1[Tz], acc);
                #pragma unroll
                for (int r=0;r<4;++r) dzt[Tz][r] = acc[r];
            }
            float px0[4] = {0,0,0,0}, px1[4] = {0,0,0,0};
            #pragma unroll
            for (int Tz=0;Tz<4;++Tz)
                #pragma unroll
                for (int r=0;r<4;++r){
                    float R = unpk_lo(rnp[Tz][r]);
                    float N = unpk_hi(rnp[Tz][r]);
                    float U = ug[Tz][r], GH = ghs[Tz][r];
                    float nb = dzt[Tz][r]*(1.f-U);
                    float dn = nb*(1.f-N*N);
                    float gnb = dn*R;
                    float rb  = dn*GH;
                    float dr  = rb*R*(1.f-R);
                    float du  = dzt[Tz][r]*(zcp[Tz][r]-N)*U*(1.f-U);
                    int o = (quad*4+r)*200 + col + 16*Tz;
                    sw[o]       = (_Float16)dr;
                    sw[o + 64]  = (_Float16)du;
                    sw[o + 128] = (_Float16)gnb;
                    px0[r] += dr*wi0[Tz] + du*wi0[Tz+4] + dn*wi0[Tz+8];
                    px1[r] += dr*wi1[Tz] + du*wi1[Tz+4] + dn*wi1[Tz+8];
                }
            v8h adg[6];
            #pragma unroll
            for (int kc=0;kc<6;++kc)
                adg[kc] = *(const v8h*)(sw + col*200 + kc*32 + quad*8);
            #pragma unroll
            for (int Tz=0;Tz<4;++Tz){
                v4f acc = { dzt[Tz][0]*ug[Tz][0], dzt[Tz][1]*ug[Tz][1],
                            dzt[Tz][2]*ug[Tz][2], dzt[Tz][3]*ug[Tz][3] };
                #pragma unroll
                for (int kc=0;kc<6;++kc){
                    v8h bwt = *(const v8h*)(regB + (Tz*6+kc)*512 + ln*8);
                    acc = MFMA16(adg[kc], bwt, acc);
                }
                #pragma unroll
                for (int r=0;r<4;++r) zbN[Tz][r] = acc[r];
            }
            #pragma unroll
            for (int r=0;r<4;++r){
                float p0 = px0[r], p1 = px1[r];
                #pragma unroll
                for (int m=1;m<16;m<<=1){ p0 += __shfl_xor(p0,m); p1 += __shfl_xor(p1,m); }
                yb0[r] += p0; yb1[r] += p1;
            }
        }
        // ---------- Adam ----------
        v2f xb = *(const v2f*)(&xw[col*16 + 8 + 2*quad]);
        float g0 = xb[0] * (-1.f/16384.f), g1 = xb[1] * (-1.f/16384.f);
        am0 = 0.9f*am0 + 0.1f*g0;        am1 = 0.9f*am1 + 0.1f*g1;
        av0 = 0.999f*av0 + 0.001f*g0*g0; av1 = 0.999f*av1 + 0.001f*g1*g1;
        pb1 *= 0.9f; pb2 *= 0.999f;
        float ic1 = 1.f/(1.f-pb1), ic2 = 1.f/(1.f-pb2);
        xa0 -= 0.1f*(am0*ic1)/(sqrtf(av0*ic2) + 1e-8f);
        xa1 -= 0.1f*(am1*ic1)/(sqrtf(av1*ic2) + 1e-8f);
        xw[col*16 + 2*quad]   = xa0;
        xw[col*16 + 2*quad+1] = xa1;
        v2f tv; tv[0]=xa0; tv[1]=xa1;
        *(v2f*)(traj + (size_t)(b0+col)*64 + s*8 + 2*quad) = tv;
    }
}

// ---------------------------------------------------------------------------
// K2: pick best step
// ---------------------------------------------------------------------------
__global__ void k_pick(const int* __restrict__ nsp,
                       const float* __restrict__ parts, int* __restrict__ best)
{
    int ln = threadIdx.x & 63;
    int ns = *nsp; if (ns > NSMAX) ns = NSMAX;
    float losses[NSMAX];
    for (int s=0;s<NSMAX;++s){
        float acc = 0.f;
        if (s < ns){
            for (int i=ln;i<1024;i+=64) acc += parts[s*1024+i];
            #pragma unroll
            for (int m=1;m<64;m<<=1) acc += __shfl_xor(acc,m);
        }
        losses[s] = -acc * (1.f/16384.f);
    }
    if (ln==0 && blockIdx.x==0){
        float lb = 1000.f; int bi = -1;
        for (int s=0;s<ns;++s) if (losses[s] < lb){ lb = losses[s]; bi = s; }
        best[0] = bi;
    }
}

// ---------------------------------------------------------------------------
// K3: final forward from x_best (6-term split; gruHi + gruLo both LDS)
// ---------------------------------------------------------------------------
__global__ __launch_bounds__(128, 1) void k_final(
    const float* __restrict__ bs,
    const float* __restrict__ wih, const float* __restrict__ whh,
    const float* __restrict__ bih, const float* __restrict__ bhh,
    const float* __restrict__ Wl1, const float* __restrict__ bl1,
    const float* __restrict__ Wl2, const float* __restrict__ bl2,
    const float* __restrict__ z0ws, const float* __restrict__ traj,
    const int* __restrict__ best, float* __restrict__ outp)
{
    __shared__ _Float16 gruHi[12288];
    __shared__ _Float16 gruLo[12288];
    __shared__ _Float16 stageL[2][3200];
    __shared__ float    xsx[2][128];

    const int tid  = threadIdx.x;
    const int w    = tid >> 6;
    const int ln   = tid & 63;
    const int col  = ln & 15;
    const int quad = ln >> 4;
    const int b0   = blockIdx.x*32 + w*16;
    _Float16* sw = stageL[w];
    float*    xw = xsx[w];

    for (int i = tid; i < 24*64; i += 128){
        int f = i>>6, l = i&63, lc = l&15, lq = l>>4;
        int T = f>>1, K = f&1;
        *(v8h*)(gruHi + f*512 + l*8) = ld8  (whh + (lc+16*T)*64 + 32*K + lq*8);
        *(v8h*)(gruLo + f*512 + l*8) = ld8lo(whh + (lc+16*T)*64 + 32*K + lq*8);
    }
    __syncthreads();

    v8h w1h[2][2], w1l[2][2];
    #pragma unroll
    for (int T=0;T<2;++T){
        int n = col + 16*T;
        w1h[T][0] = ld8s  (Wl1 + (     quad*8)*32 + n, 32);
        w1h[T][1] = ld8s  (Wl1 + (32 + quad*8)*32 + n, 32);
        w1l[T][0] = ld8slo(Wl1 + (     quad*8)*32 + n, 32);
        w1l[T][1] = ld8slo(Wl1 + (32 + quad*8)*32 + n, 32);
    }
    float wi0[12], wi1[12], bsum[8], bn_i[4], bn_h[4];
    #pragma unroll
    for (int T=0;T<12;++T){
        int c = col + 16*T;
        wi0[T] = wih[c*2]; wi1[T] = wih[c*2+1];
    }
    #pragma unroll
    for (int T=0;T<8;++T) bsum[T] = bih[col+16*T] + bhh[col+16*T];
    #pragma unroll
    for (int T=0;T<4;++T){
        bn_i[T] = bih[128+col+16*T];
        bn_h[T] = bhh[128+col+16*T];
    }
    float w2[2][4], bl1v[2];
    #pragma unroll
    for (int T=0;T<2;++T){
        int i5 = col + 16*T;
        bl1v[T] = bl1[i5];
        #pragma unroll
        for (int j=0;j<4;++j) w2[T][j] = Wl2[i5*4+j];
    }
    float b2[4] = {bl2[0], bl2[1], bl2[2], bl2[3]};

    float zc[4][4];
    #pragma unroll
    for (int Tz=0;Tz<4;++Tz)
        #pragma unroll
        for (int r=0;r<4;++r){
            float v = z0ws[(size_t)(b0+quad*4+r)*64 + col + 16*Tz];
            zc[Tz][r] = v;
            _Float16 h = (_Float16)v;
            int o = (quad*4+r)*200 + col + 16*Tz;
            sw[o] = h; sw[o+64] = (_Float16)(v-(float)h);
        }

    int bi = best[0];
    float x0i, x1i;
    if (bi >= 0){
        v2f xv = *(const v2f*)(traj + (size_t)(b0+col)*64 + bi*8 + 2*quad);
        x0i = xv[0]; x1i = xv[1];
    } else { x0i = bs[2*quad]; x1i = bs[2*quad+1]; }
    xw[col*8 + 2*quad]   = x0i;
    xw[col*8 + 2*quad+1] = x1i;

    float y0[4]={0,0,0,0}, y1[4]={0,0,0,0};
    #pragma unroll
    for (int t=0;t<4;++t){
        v8h ah0 = *(const v8h*)(sw + col*200 +      quad*8);
        v8h ah1 = *(const v8h*)(sw + col*200 + 32 + quad*8);
        v8h al0 = *(const v8h*)(sw + col*200 + 64 + quad*8);
        v8h al1 = *(const v8h*)(sw + col*200 + 96 + quad*8);
        #pragma unroll
        for (int Tz=0;Tz<4;++Tz){
            v4f g3[3];
            #pragma unroll
            for (int gg=0; gg<3; ++gg){
                int tg = Tz + 4*gg;
                v8h h0 = *(const v8h*)(gruHi + (tg*2  )*512 + ln*8);
                v8h h1 = *(const v8h*)(gruHi + (tg*2+1)*512 + ln*8);
                v8h l0 = *(const v8h*)(gruLo + (tg*2  )*512 + ln*8);
                v8h l1 = *(const v8h*)(gruLo + (tg*2+1)*512 + ln*8);
                v4f acc = {0,0,0,0};
                acc = MFMA16(ah0, l0, acc);
                acc = MFMA16(ah1, l1, acc);
                acc = MFMA16(al0, h0, acc);
                acc = MFMA16(al1, h1, acc);
                acc = MFMA16(ah0, h0, acc);
                acc = MFMA16(ah1, h1, acc);
                g3[gg] = acc;
            }
            #pragma unroll
            for (int r=0;r<4;++r){
                float pr = g3[0][r] + wi0[Tz]*y0[r]   + wi1[Tz]*y1[r]   + bsum[Tz];
                float pu = g3[1][r] + wi0[Tz+4]*y0[r] + wi1[Tz+4]*y1[r] + bsum[Tz+4];
                float gh = g3[2][r] + bn_h[Tz];
                float gi = wi0[Tz+8]*y0[r] + wi1[Tz+8]*y1[r] + bn_i[Tz];
                float R = fsigm(pr), U = fsigm(pu);
                float N = ftanh(gi + R*gh);
                zc[Tz][r] = (1.f-U)*N + U*zc[Tz][r];
            }
        }
        #pragma unroll
        for (int Tz=0;Tz<4;++Tz)
            #pragma unroll
            for (int r=0;r<4;++r){
                float v = zc[Tz][r];
                _Float16 h = (_Float16)v;
                int o = (quad*4+r)*200 + col + 16*Tz;
                sw[o] = h; sw[o+64] = (_Float16)(v-(float)h);
            }
        v8h bh0 = *(const v8h*)(sw + col*200 +      quad*8);
        v8h bh1 = *(const v8h*)(sw + col*200 + 32 + quad*8);
        v8h bl0 = *(const v8h*)(sw + col*200 + 64 + quad*8);
        v8h blf = *(const v8h*)(sw + col*200 + 96 + quad*8);
        float aaf[2][4];
        #pragma unroll
        for (int T=0;T<2;++T){
            v4f acc = {0.f,0.f,0.f,0.f};
            acc = MFMA16(bh0, w1l[T][0], acc);
            acc = MFMA16(bh1, w1l[T][1], acc);
            acc = MFMA16(bl0, w1h[T][0], acc);
            acc = MFMA16(blf, w1h[T][1], acc);
            acc = MFMA16(bh0, w1h[T][0], acc);
            acc = MFMA16(bh1, w1h[T][1], acc);
            #pragma unroll
            for (int r=0;r<4;++r) aaf[T][r] = fmaxf(acc[r] + bl1v[T], 0.f);
        }
        #pragma unroll
        for (int r=0;r<4;++r){
            float q0 = aaf[0][r]*w2[0][0] + aaf[1][r]*w2[1][0];
            float q1 = aaf[0][r]*w2[0][1] + aaf[1][r]*w2[1][1];
            float q2 = aaf[0][r]*w2[0][2] + aaf[1][r]*w2[1][2];
            float q3 = aaf[0][r]*w2[0][3] + aaf[1][r]*w2[1][3];
            #pragma unroll
            for (int m=1;m<16;m<<=1){
                q0 += __shfl_xor(q0,m); q1 += __shfl_xor(q1,m);
                q2 += __shfl_xor(q2,m); q3 += __shfl_xor(q3,m);
            }
            float c0 = q0 + b2[0], c1 = q1 + b2[1];
            float s0 = fsp(q2 + b2[2]) + 0.001f;
            float s1 = fsp(q3 + b2[3]) + 0.001f;
            float xv0 = xw[(quad*4+r)*8 + 2*t];
            float xv1 = xw[(quad*4+r)*8 + 2*t + 1];
            y0[r] += c0 + s0*xv0;
            y1[r] += c1 + s1*xv1;
            if (col == 0){
                v2f o; o[0]=y0[r]; o[1]=y1[r];
                *(v2f*)(outp + (size_t)(b0+quad*4+r)*8 + 2*t) = o;
            }
        }
    }
}

// ---------------------------------------------------------------------------
extern "C" void kernel_launch(void* const* d_in, const int* in_sizes, int n_in,
                              void* d_out, int out_size, void* d_ws, size_t ws_size,
                              hipStream_t stream)
{
    const float* visual = (const float*)d_in[0];
    const float* vel    = (const float*)d_in[1];
    const float* tl     = (const float*)d_in[2];
    const float* tls    = (const float*)d_in[3];
    const float* goal   = (const float*)d_in[4];
    const float* bs     = (const float*)d_in[5];
    const float* Wm1    = (const float*)d_in[6];
    const float* bm1    = (const float*)d_in[7];
    const float* Wm2    = (const float*)d_in[8];
    const float* bm2    = (const float*)d_in[9];
    const float* Wm3    = (const float*)d_in[10];
    const float* bm3    = (const float*)d_in[11];
    const float* wih    = (const float*)d_in[12];
    const float* whh    = (const float*)d_in[13];
    const float* bih    = (const float*)d_in[14];
    const float* bhh    = (const float*)d_in[15];
    const float* Wl1    = (const float*)d_in[16];
    const float* bl1    = (const float*)d_in[17];
    const float* Wl2    = (const float*)d_in[18];
    const float* bl2    = (const float*)d_in[19];
    const int*   nsp    = (const int*)d_in[20];

    float* z0ws  = (float*)d_ws;                        // B*64 f32
    float* traj  = z0ws + (size_t)BATCH * 64;           // B*64 f32
    float* parts = traj + (size_t)BATCH * 64;           // 8*1024 f32
    int*   best  = (int*)(parts + NSMAX*1024);          // 4 ints (pad)
    _Float16* ckpt = (_Float16*)(best + 4);             // 3*B*64 f16

    k_mlp<<<BATCH/8, 512, 0, stream>>>(visual, vel, tl, tls,
        Wm1, bm1, Wm2, bm2, Wm3, bm3, z0ws);

    k_adam<<<BATCH/32, 128, 0, stream>>>(goal, bs,
        wih, whh, bih, bhh, Wl1, bl1, Wl2, bl2,
        nsp, z0ws, traj, parts, ckpt);

    k_pick<<<1, 64, 0, stream>>>(nsp, parts, best);

    k_final<<<BATCH/32, 128, 0, stream>>>(bs,
        wih, whh, bih, bhh, Wl1, bl1, Wl2, bl2,
        z0ws, traj, best, (float*)d_out);
}

// Round 9
// 758.109 us; speedup vs baseline: 2.4220x; 2.4220x over previous
//
#include <hip/hip_runtime.h>
#include <math.h>

#define BATCH 16384
#define NSMAX 8
#define LOG2PI_F 1.8378770664093453f
#define LOG4_F 1.3862943611198906f

typedef _Float16 v8h __attribute__((ext_vector_type(8)));
typedef _Float16 v2h __attribute__((ext_vector_type(2)));
typedef float    v4f __attribute__((ext_vector_type(4)));
typedef float    v2f __attribute__((ext_vector_type(2)));

#define MFMA16(A,B,C) __builtin_amdgcn_mfma_f32_16x16x32_f16(A,B,C,0,0,0)

__device__ __forceinline__ float bcast(float v, int l) {
    return __uint_as_float(__builtin_amdgcn_readlane(__float_as_uint(v), (unsigned)l));
}
__device__ __forceinline__ float fsigm(float v){ return 1.f/(1.f + __expf(-v)); }
__device__ __forceinline__ float ftanh(float v){ return 1.f - 2.f/(__expf(2.f*v)+1.f); }
__device__ __forceinline__ float fsp(float v){ return fmaxf(v,0.f) + __logf(1.f + __expf(-fabsf(v))); }

__device__ __forceinline__ v8h ld8(const float* p){
    v4f a = *(const v4f*)p; v4f b = *(const v4f*)(p+4);
    v8h r;
    r[0]=(_Float16)a[0]; r[1]=(_Float16)a[1]; r[2]=(_Float16)a[2]; r[3]=(_Float16)a[3];
    r[4]=(_Float16)b[0]; r[5]=(_Float16)b[1]; r[6]=(_Float16)b[2]; r[7]=(_Float16)b[3];
    return r;
}
__device__ __forceinline__ v8h ld8lo(const float* p){
    v4f a = *(const v4f*)p; v4f b = *(const v4f*)(p+4);
    v8h r;
    #pragma unroll
    for (int j=0;j<4;++j){ _Float16 h=(_Float16)a[j]; r[j]=(_Float16)(a[j]-(float)h); }
    #pragma unroll
    for (int j=0;j<4;++j){ _Float16 h=(_Float16)b[j]; r[4+j]=(_Float16)(b[j]-(float)h); }
    return r;
}
__device__ __forceinline__ v8h ld8s(const float* p, int stride){
    v8h r;
    #pragma unroll
    for (int j=0;j<8;++j) r[j] = (_Float16)p[j*stride];
    return r;
}
__device__ __forceinline__ v8h ld8slo(const float* p, int stride){
    v8h r;
    #pragma unroll
    for (int j=0;j<8;++j){ float v=p[j*stride]; _Float16 h=(_Float16)v; r[j]=(_Float16)(v-(float)h); }
    return r;
}

// ---------------------------------------------------------------------------
// K-1: pre-convert whh into fp16 frag images (gHi/gLo/gT) in d_ws.
// Consumers copy these with contiguous coalesced v8h reads — kills the
// 512-block strided-read contention of R6's per-step fills.
// ---------------------------------------------------------------------------
__global__ void k_prep(const float* __restrict__ whh,
                       _Float16* __restrict__ gHiG,
                       _Float16* __restrict__ gLoG,
                       _Float16* __restrict__ gTG)
{
    int i = blockIdx.x*256 + threadIdx.x;
    if (i < 1536){
        int f = i>>6, l = i&63, lc = l&15, lq = l>>4;
        int T = f>>1, K = f&1;
        *(v8h*)(gHiG + (size_t)f*512 + l*8) = ld8  (whh + (lc+16*T)*64 + 32*K + lq*8);
        *(v8h*)(gLoG + (size_t)f*512 + l*8) = ld8lo(whh + (lc+16*T)*64 + 32*K + lq*8);
        int Tz = f/6, kc = f - Tz*6;
        *(v8h*)(gTG  + (size_t)f*512 + l*8) = ld8s(whh + (kc*32+lq*8)*64 + lc + 16*Tz, 64);
    }
}

// ---------------------------------------------------------------------------
// K0: MLP -> z0 (fp32 scalar, proven)
// ---------------------------------------------------------------------------
__global__ __launch_bounds__(512) void k_mlp(
    const float* __restrict__ visual, const float* __restrict__ vel,
    const float* __restrict__ tl, const float* __restrict__ tls,
    const float* __restrict__ Wm1, const float* __restrict__ bm1,
    const float* __restrict__ Wm2, const float* __restrict__ bm2,
    const float* __restrict__ Wm3, const float* __restrict__ bm3,
    float* __restrict__ z0ws)
{
    __shared__ float smem[9600];
    const int tid  = threadIdx.x;
    const int lane = tid & 63;
    const int w    = tid >> 6;
    const int b    = blockIdx.x * 8 + w;
    for (int i = tid; i < 8512; i += 512) smem[i] = Wm1[i];
    float* sfeat = smem + 8512 + w * 136;
    sfeat[lane]      = visual[b*128 + lane];
    sfeat[64 + lane] = visual[b*128 + 64 + lane];
    if (lane < 3)  sfeat[128 + lane] = vel[b*3 + lane];
    if (lane == 3) sfeat[131] = tl[b];
    if (lane == 4) sfeat[132] = tls[b];
    __syncthreads();
    float acc = bm1[lane];
    for (int f = 0; f < 133; ++f) acc = fmaf(smem[f*64 + lane], sfeat[f], acc);
    float z1 = fmaxf(acc, 0.f);
    __syncthreads();
    for (int i = tid; i < 4096; i += 512) smem[i] = Wm2[i];
    __syncthreads();
    acc = bm2[lane];
    #pragma unroll 8
    for (int kk = 0; kk < 64; ++kk) acc = fmaf(smem[kk*64 + lane], bcast(z1, kk), acc);
    float z2 = fmaxf(acc, 0.f);
    __syncthreads();
    for (int i = tid; i < 4096; i += 512) smem[i] = Wm3[i];
    __syncthreads();
    acc = bm3[lane];
    #pragma unroll 8
    for (int kk = 0; kk < 64; ++kk) acc = fmaf(smem[kk*64 + lane], bcast(z2, kk), acc);
    z0ws[(size_t)b*64 + lane] = fmaxf(acc, 0.f);
}

// ---------------------------------------------------------------------------
// K1: MFMA flow — R6-verbatim structure (proven correct/deterministic),
// EXCEPT fills are coalesced copies from k_prep images. 2 waves/block,
// wave = 16 elements, grid 512.
// ---------------------------------------------------------------------------
__global__ __launch_bounds__(128, 1) void k_adam(
    const float* __restrict__ goal, const float* __restrict__ bs,
    const float* __restrict__ wih, const float* __restrict__ whh,
    const float* __restrict__ bih, const float* __restrict__ bhh,
    const float* __restrict__ Wl1, const float* __restrict__ bl1,
    const float* __restrict__ Wl2, const float* __restrict__ bl2,
    const int*  __restrict__ nsp, const float* __restrict__ z0ws,
    _Float16* __restrict__ traj16, float* __restrict__ parts,
    _Float16* __restrict__ ckpt,
    const _Float16* __restrict__ gHiG, const _Float16* __restrict__ gLoG,
    const _Float16* __restrict__ gTG)
{
    __shared__ _Float16 gruHi[12288];     // hi(whh) frag-ordered, 24KB
    __shared__ _Float16 regB [12288];     // swap: gruLo (fwd) / whhT (bwd), 24KB
    __shared__ _Float16 stageL[2][3200];  // per-wave stage, stride 200 halfs
    __shared__ float    xsx[2][256];      // per-wave x / xbar

    const int tid  = threadIdx.x;
    const int w    = tid >> 6;
    const int ln   = tid & 63;
    const int col  = ln & 15;
    const int quad = ln >> 4;
    const int b0   = blockIdx.x*32 + w*16;
    _Float16* sw = stageL[w];
    float*    xw = xsx[w];

    // one-time: gruHi <- image (coalesced)
    for (int i=tid;i<1536;i+=128)
        *(v8h*)(gruHi + i*8) = *(const v8h*)(gHiG + (size_t)i*8);

    // ---- register weights (R6-exact set) ----
    v8h w1h[2][2], w1l[2][2];
    #pragma unroll
    for (int T=0;T<2;++T){
        int n = col + 16*T;
        w1h[T][0] = ld8s  (Wl1 + (     quad*8)*32 + n, 32);
        w1h[T][1] = ld8s  (Wl1 + (32 + quad*8)*32 + n, 32);
        w1l[T][0] = ld8slo(Wl1 + (     quad*8)*32 + n, 32);
        w1l[T][1] = ld8slo(Wl1 + (32 + quad*8)*32 + n, 32);
    }
    v8h awl1[4];
    #pragma unroll
    for (int Tz=0;Tz<4;++Tz)
        awl1[Tz] = ld8(Wl1 + (col+16*Tz)*32 + quad*8);

    float wi0[12], wi1[12];
    #pragma unroll
    for (int T=0;T<12;++T){
        int c = col + 16*T;
        wi0[T] = wih[c*2]; wi1[T] = wih[c*2+1];
    }
    float bsum[8], bn_i[4], bn_h[4];
    #pragma unroll
    for (int T=0;T<8;++T) bsum[T] = bih[col+16*T] + bhh[col+16*T];
    #pragma unroll
    for (int T=0;T<4;++T){
        bn_i[T] = bih[128+col+16*T];
        bn_h[T] = bhh[128+col+16*T];
    }
    float w2[2][4], bl1v[2];
    #pragma unroll
    for (int T=0;T<2;++T){
        int i5 = col + 16*T;
        bl1v[T] = bl1[i5];
        #pragma unroll
        for (int j=0;j<4;++j) w2[T][j] = Wl2[i5*4+j];
    }
    float b2[4] = {bl2[0], bl2[1], bl2[2], bl2[3]};

    float xa0 = bs[2*quad], xa1 = bs[2*quad+1];
    xw[col*16 + 2*quad]   = xa0;
    xw[col*16 + 2*quad+1] = xa1;
    float am0=0,am1=0,av0=0,av1=0,pb1=1.f,pb2=1.f;

    int ns = *nsp; if (ns > NSMAX) ns = NSMAX;

    _Float16 rg[4][4], ug[4][4], ngv[4][4];
    float ghs[4][4], aa[2][4];
    float s0v[4], s1v[4], c0v[4], c1v[4];
    float zc[4][4];

    auto cell = [&](bool split, const float (&yp0)[4], const float (&yp1)[4],
                    const float (&zprev)[4][4]){
        v8h ah0 = *(const v8h*)(sw + col*200 +      quad*8);
        v8h ah1 = *(const v8h*)(sw + col*200 + 32 + quad*8);
        v8h al0, al1;
        if (split){
            al0 = *(const v8h*)(sw + col*200 + 64 + quad*8);
            al1 = *(const v8h*)(sw + col*200 + 96 + quad*8);
        }
        float znew[4][4];
        #pragma unroll
        for (int Tz=0;Tz<4;++Tz){
            v4f g3[3];
            #pragma unroll
            for (int gg=0; gg<3; ++gg){
                int tg = Tz + 4*gg;
                v8h h0 = *(const v8h*)(gruHi + (tg*2  )*512 + ln*8);
                v8h h1 = *(const v8h*)(gruHi + (tg*2+1)*512 + ln*8);
                v4f acc = {0,0,0,0};
                if (split){
                    v8h l0 = *(const v8h*)(regB + (tg*2  )*512 + ln*8);
                    v8h l1 = *(const v8h*)(regB + (tg*2+1)*512 + ln*8);
                    acc = MFMA16(ah0, l0, acc);
                    acc = MFMA16(ah1, l1, acc);
                    acc = MFMA16(al0, h0, acc);
                    acc = MFMA16(al1, h1, acc);
                }
                acc = MFMA16(ah0, h0, acc);
                acc = MFMA16(ah1, h1, acc);
                g3[gg] = acc;
            }
            #pragma unroll
            for (int r=0;r<4;++r){
                float pr = g3[0][r] + wi0[Tz]*yp0[r]   + wi1[Tz]*yp1[r]   + bsum[Tz];
                float pu = g3[1][r] + wi0[Tz+4]*yp0[r] + wi1[Tz+4]*yp1[r] + bsum[Tz+4];
                float gh = g3[2][r] + bn_h[Tz];
                float gi = wi0[Tz+8]*yp0[r] + wi1[Tz+8]*yp1[r] + bn_i[Tz];
                float R = fsigm(pr), U = fsigm(pu);
                float N = ftanh(gi + R*gh);
                if (!split){
                    rg[Tz][r]=(_Float16)R; ug[Tz][r]=(_Float16)U;
                    ngv[Tz][r]=(_Float16)N; ghs[Tz][r]=gh;
                }
                znew[Tz][r] = (1.f-U)*N + U*zprev[Tz][r];
            }
        }
        if (split){
            #pragma unroll
            for (int Tz=0;Tz<4;++Tz)
                #pragma unroll
                for (int r=0;r<4;++r){
                    float v = znew[Tz][r];
                    zc[Tz][r] = v;
                    _Float16 h = (_Float16)v;
                    int o = (quad*4+r)*200 + col + 16*Tz;
                    sw[o] = h; sw[o+64] = (_Float16)(v-(float)h);
                }
        } else {
            #pragma unroll
            for (int Tz=0;Tz<4;++Tz)
                #pragma unroll
                for (int r=0;r<4;++r)
                    sw[(quad*4+r)*200 + col + 16*Tz] = (_Float16)znew[Tz][r];
        }
        v8h bh0 = *(const v8h*)(sw + col*200 +      quad*8);
        v8h bh1 = *(const v8h*)(sw + col*200 + 32 + quad*8);
        v8h bl0, blf;
        if (split){
            bl0 = *(const v8h*)(sw + col*200 + 64 + quad*8);
            blf = *(const v8h*)(sw + col*200 + 96 + quad*8);
        }
        #pragma unroll
        for (int T=0;T<2;++T){
            v4f acc = {0.f,0.f,0.f,0.f};
            acc = MFMA16(bh0, w1l[T][0], acc);
            acc = MFMA16(bh1, w1l[T][1], acc);
            if (split){
                acc = MFMA16(bl0, w1h[T][0], acc);
                acc = MFMA16(blf, w1h[T][1], acc);
            }
            acc = MFMA16(bh0, w1h[T][0], acc);
            acc = MFMA16(bh1, w1h[T][1], acc);
            #pragma unroll
            for (int r=0;r<4;++r) aa[T][r] = fmaxf(acc[r] + bl1v[T], 0.f);
        }
        #pragma unroll
        for (int r=0;r<4;++r){
            float q2 = aa[0][r]*w2[0][2] + aa[1][r]*w2[1][2];
            float q3 = aa[0][r]*w2[0][3] + aa[1][r]*w2[1][3];
            float q0 = 0.f, q1 = 0.f;
            if (split){
                q0 = aa[0][r]*w2[0][0] + aa[1][r]*w2[1][0];
                q1 = aa[0][r]*w2[0][1] + aa[1][r]*w2[1][1];
            }
            #pragma unroll
            for (int m=1;m<16;m<<=1){
                q2 += __shfl_xor(q2,m); q3 += __shfl_xor(q3,m);
                if (split){ q0 += __shfl_xor(q0,m); q1 += __shfl_xor(q1,m); }
            }
            if (split){ c0v[r] = q0 + b2[0]; c1v[r] = q1 + b2[1]; }
            s0v[r] = fsp(q2 + b2[2]) + 0.001f;
            s1v[r] = fsp(q3 + b2[3]) + 0.001f;
        }
    };

    const int crow = ln >> 2;
    const int ccol = (ln & 3) * 16;

    for (int s=0; s<ns; ++s){
        __syncthreads();                 // prior-phase regB reads (and init) done
        for (int i=tid;i<1536;i+=128)    // regB = gruLo (coalesced copy)
            *(v8h*)(regB + i*8) = *(const v8h*)(gLoG + (size_t)i*8);
        __syncthreads();
        // reset z to z0 (stage split)
        #pragma unroll
        for (int Tz=0;Tz<4;++Tz)
            #pragma unroll
            for (int r=0;r<4;++r){
                float v = z0ws[(size_t)(b0+quad*4+r)*64 + col + 16*Tz];
                zc[Tz][r] = v;
                _Float16 h = (_Float16)v;
                int o = (quad*4+r)*200 + col + 16*Tz;
                sw[o] = h; sw[o+64] = (_Float16)(v-(float)h);
            }
        // ---------- forward ----------
        float y0[4]={0,0,0,0}, y1[4]={0,0,0,0};
        float sumls[4]={0,0,0,0}, sumx2[4]={0,0,0,0};
        #pragma unroll
        for (int t=0;t<4;++t){
            float zprev[4][4];
            #pragma unroll
            for (int Tz=0;Tz<4;++Tz)
                #pragma unroll
                for (int r=0;r<4;++r) zprev[Tz][r] = zc[Tz][r];
            cell(true, y0, y1, zprev);
            #pragma unroll
            for (int r=0;r<4;++r){
                v2f xv = *(const v2f*)(&xw[(quad*4+r)*16 + 2*t]);
                sumx2[r] += xv[0]*xv[0] + xv[1]*xv[1];
                y0[r] += c0v[r] + s0v[r]*xv[0];
                y1[r] += c1v[r] + s1v[r]*xv[1];
                int o = (quad*4+r)*200 + 192 + 2*t;
                sw[o] = (_Float16)y0[r]; sw[o+1] = (_Float16)y1[r];
                sumls[r] += __logf(s0v[r]) + __logf(s1v[r]);
            }
            if (t<3){
                v8h z1 = *(const v8h*)(sw + crow*200 + ccol);
                v8h z2 = *(const v8h*)(sw + crow*200 + ccol + 8);
                _Float16* gp = ckpt + ((size_t)t*BATCH + (b0+crow))*64 + ccol;
                *(v8h*)gp = z1; *(v8h*)(gp+8) = z2;
            }
        }
        // ---------- loss + y-grad ----------
        float cel[4], yb0[4], yb1[4];
        #pragma unroll
        for (int r=0;r<4;++r){
            const float* gpt = goal + (size_t)(b0+quad*4+r)*8;
            v4f ga = *(const v4f*)gpt; v4f gb = *(const v4f*)(gpt+4);
            float c0_ = -0.5f*((y0[r]-ga[0])*(y0[r]-ga[0]) + (y1[r]-ga[1])*(y1[r]-ga[1])) - LOG2PI_F;
            float c1_ = -0.5f*((y0[r]-ga[2])*(y0[r]-ga[2]) + (y1[r]-ga[3])*(y1[r]-ga[3])) - LOG2PI_F;
            float c2_ = -0.5f*((y0[r]-gb[0])*(y0[r]-gb[0]) + (y1[r]-gb[1])*(y1[r]-gb[1])) - LOG2PI_F;
            float c3_ = -0.5f*((y0[r]-gb[2])*(y0[r]-gb[2]) + (y1[r]-gb[3])*(y1[r]-gb[3])) - LOG2PI_F;
            float mx = fmaxf(fmaxf(c0_,c1_), fmaxf(c2_,c3_));
            float e0 = __expf(c0_-mx), e1 = __expf(c1_-mx), e2 = __expf(c2_-mx), e3 = __expf(c3_-mx);
            float se = e0+e1+e2+e3;
            float lp = mx + __logf(se) - LOG4_F;
            cel[r] = -0.5f*sumx2[r] - 4.f*LOG2PI_F - sumls[r] + lp;
            float inv = 1.f/se;
            yb0[r] = inv*(e0*(ga[0]-y0[r]) + e1*(ga[2]-y0[r]) + e2*(gb[0]-y0[r]) + e3*(gb[2]-y0[r]));
            yb1[r] = inv*(e0*(ga[1]-y1[r]) + e1*(ga[3]-y1[r]) + e2*(gb[1]-y1[r]) + e3*(gb[3]-y1[r]));
        }
        float tsum = cel[0]+cel[1]+cel[2]+cel[3];
        tsum += __shfl_xor(tsum,16); tsum += __shfl_xor(tsum,32);
        if (ln==0) parts[s*1024 + blockIdx.x*2 + w] = tsum;

        __syncthreads();                 // fwd regB reads done
        for (int i=tid;i<1536;i+=128)    // regB = whhT (coalesced copy)
            *(v8h*)(regB + i*8) = *(const v8h*)(gTG + (size_t)i*8);
        __syncthreads();

        // ---------- backward ----------
        float zbN[4][4];
        #pragma unroll
        for (int Tz=0;Tz<4;++Tz){ zbN[Tz][0]=0;zbN[Tz][1]=0;zbN[Tz][2]=0;zbN[Tz][3]=0; }
        #pragma unroll
        for (int tt=0; tt<4; ++tt){
            const int t = 3-tt;
            float zcp[4][4];
            if (t > 0){
                const _Float16* gp = ckpt + ((size_t)(t-1)*BATCH + (b0+crow))*64 + ccol;
                v8h z1 = *(const v8h*)gp; v8h z2 = *(const v8h*)(gp+8);
                *(v8h*)(sw + crow*200 + ccol)     = z1;
                *(v8h*)(sw + crow*200 + ccol + 8) = z2;
                #pragma unroll
                for (int Tz=0;Tz<4;++Tz)
                    #pragma unroll
                    for (int r=0;r<4;++r)
                        zcp[Tz][r] = (float)sw[(quad*4+r)*200 + col + 16*Tz];
            } else {
                #pragma unroll
                for (int Tz=0;Tz<4;++Tz)
                    #pragma unroll
                    for (int r=0;r<4;++r){
                        _Float16 h = (_Float16)z0ws[(size_t)(b0+quad*4+r)*64 + col + 16*Tz];
                        zcp[Tz][r] = (float)h;
                        sw[(quad*4+r)*200 + col + 16*Tz] = h;
                    }
            }
            float yp0[4], yp1[4];
            #pragma unroll
            for (int r=0;r<4;++r){
                if (t==0){ yp0[r]=0.f; yp1[r]=0.f; }
                else {
                    int o = (quad*4+r)*200 + 192 + 2*(t-1);
                    yp0[r] = (float)sw[o]; yp1[r] = (float)sw[o+1];
                }
            }
            cell(false, yp0, yp1, zcp);

            float l2[4], l3[4];
            #pragma unroll
            for (int r=0;r<4;++r){
                v2f xv = *(const v2f*)(&xw[(quad*4+r)*16 + 2*t]);
                float sb0 = yb0[r]*xv[0] - 1.f/s0v[r];
                float sb1 = yb1[r]*xv[1] - 1.f/s1v[r];
                float sg0 = 1.f - __expf(-(s0v[r]-0.001f));
                float sg1 = 1.f - __expf(-(s1v[r]-0.001f));
                l2[r] = sb0*sg0; l3[r] = sb1*sg1;
                v2f xb; xb[0] = yb0[r]*s0v[r] - xv[0]; xb[1] = yb1[r]*s1v[r] - xv[1];
                *(v2f*)(&xw[(quad*4+r)*16 + 8 + 2*t]) = xb;
            }
            #pragma unroll
            for (int T=0;T<2;++T)
                #pragma unroll
                for (int r=0;r<4;++r){
                    float ab = w2[T][0]*yb0[r] + w2[T][1]*yb1[r] + w2[T][2]*l2[r] + w2[T][3]*l3[r];
                    ab = (aa[T][r] > 0.f) ? ab : 0.f;
                    sw[(quad*4+r)*200 + 128 + col + 16*T] = (_Float16)ab;
                }
            v8h a_ab = *(const v8h*)(sw + col*200 + 128 + quad*8);
            float dzt[4][4];
            #pragma unroll
            for (int Tz=0;Tz<4;++Tz){
                v4f acc = { zbN[Tz][0], zbN[Tz][1], zbN[Tz][2], zbN[Tz][3] };
                acc = MFMA16(a_ab, awl1[Tz], acc);
                #pragma unroll
                for (int r=0;r<4;++r) dzt[Tz][r] = acc[r];
            }
            float px0[4] = {0,0,0,0}, px1[4] = {0,0,0,0};
            #pragma unroll
            for (int Tz=0;Tz<4;++Tz)
                #pragma unroll
                for (int r=0;r<4;++r){
                    float R = (float)rg[Tz][r];
                    float N = (float)ngv[Tz][r];
                    float U = (float)ug[Tz][r];
                    float GH= ghs[Tz][r];
                    float nb = dzt[Tz][r]*(1.f-U);
                    float dn = nb*(1.f-N*N);
                    float gnb = dn*R;
                    float rb  = dn*GH;
                    float dr  = rb*R*(1.f-R);
                    float du  = dzt[Tz][r]*(zcp[Tz][r]-N)*U*(1.f-U);
                    int o = (quad*4+r)*200 + col + 16*Tz;
                    sw[o]       = (_Float16)dr;
                    sw[o + 64]  = (_Float16)du;
                    sw[o + 128] = (_Float16)gnb;
                    px0[r] += dr*wi0[Tz] + du*wi0[Tz+4] + dn*wi0[Tz+8];
                    px1[r] += dr*wi1[Tz] + du*wi1[Tz+4] + dn*wi1[Tz+8];
                }
            v8h adg[6];
            #pragma unroll
            for (int kc=0;kc<6;++kc)
                adg[kc] = *(const v8h*)(sw + col*200 + kc*32 + quad*8);
            #pragma unroll
            for (int Tz=0;Tz<4;++Tz){
                v4f acc;
                #pragma unroll
                for (int r=0;r<4;++r) acc[r] = dzt[Tz][r]*(float)ug[Tz][r];
                #pragma unroll
                for (int kc=0;kc<6;++kc){
                    v8h bwt = *(const v8h*)(regB + (Tz*6+kc)*512 + ln*8);
                    acc = MFMA16(adg[kc], bwt, acc);
                }
                #pragma unroll
                for (int r=0;r<4;++r) zbN[Tz][r] = acc[r];
            }
            #pragma unroll
            for (int r=0;r<4;++r){
                float p0 = px0[r], p1 = px1[r];
                #pragma unroll
                for (int m=1;m<16;m<<=1){ p0 += __shfl_xor(p0,m); p1 += __shfl_xor(p1,m); }
                yb0[r] += p0; yb1[r] += p1;
            }
        }
        // ---------- Adam ----------
        v2f xb = *(const v2f*)(&xw[col*16 + 8 + 2*quad]);
        float g0 = xb[0] * (-1.f/16384.f), g1 = xb[1] * (-1.f/16384.f);
        am0 = 0.9f*am0 + 0.1f*g0;        am1 = 0.9f*am1 + 0.1f*g1;
        av0 = 0.999f*av0 + 0.001f*g0*g0; av1 = 0.999f*av1 + 0.001f*g1*g1;
        pb1 *= 0.9f; pb2 *= 0.999f;
        float ic1 = 1.f/(1.f-pb1), ic2 = 1.f/(1.f-pb2);
        xa0 -= 0.1f*(am0*ic1)/(sqrtf(av0*ic2) + 1e-8f);
        xa1 -= 0.1f*(am1*ic1)/(sqrtf(av1*ic2) + 1e-8f);
        xw[col*16 + 2*quad]   = xa0;
        xw[col*16 + 2*quad+1] = xa1;
        v2h tv; tv[0]=(_Float16)xa0; tv[1]=(_Float16)xa1;
        *(v2h*)(traj16 + (size_t)(b0+col)*64 + s*8 + 2*quad) = tv;
    }
}

// ---------------------------------------------------------------------------
// K2: pick best step
// ---------------------------------------------------------------------------
__global__ void k_pick(const int* __restrict__ nsp,
                       const float* __restrict__ parts, int* __restrict__ best)
{
    int ln = threadIdx.x & 63;
    int ns = *nsp; if (ns > NSMAX) ns = NSMAX;
    float losses[NSMAX];
    for (int s=0;s<NSMAX;++s){
        float acc = 0.f;
        if (s < ns){
            for (int i=ln;i<1024;i+=64) acc += parts[s*1024+i];
            #pragma unroll
            for (int m=1;m<64;m<<=1) acc += __shfl_xor(acc,m);
        }
        losses[s] = -acc * (1.f/16384.f);
    }
    if (ln==0 && blockIdx.x==0){
        float lb = 1000.f; int bi = -1;
        for (int s=0;s<ns;++s) if (losses[s] < lb){ lb = losses[s]; bi = s; }
        best[0] = bi;
    }
}

// ---------------------------------------------------------------------------
// K3: final forward from x_best — R6-verbatim, fills from images, traj f16
// ---------------------------------------------------------------------------
__global__ __launch_bounds__(128, 1) void k_final(
    const float* __restrict__ bs,
    const float* __restrict__ wih, const float* __restrict__ whh,
    const float* __restrict__ bih, const float* __restrict__ bhh,
    const float* __restrict__ Wl1, const float* __restrict__ bl1,
    const float* __restrict__ Wl2, const float* __restrict__ bl2,
    const float* __restrict__ z0ws, const _Float16* __restrict__ traj16,
    const int* __restrict__ best,
    const _Float16* __restrict__ gHiG, const _Float16* __restrict__ gLoG,
    float* __restrict__ outp)
{
    __shared__ _Float16 gruHi[12288];
    __shared__ _Float16 gruLo[12288];
    __shared__ _Float16 stageL[2][3200];
    __shared__ float    xsx[2][128];

    const int tid  = threadIdx.x;
    const int w    = tid >> 6;
    const int ln   = tid & 63;
    const int col  = ln & 15;
    const int quad = ln >> 4;
    const int b0   = blockIdx.x*32 + w*16;
    _Float16* sw = stageL[w];
    float*    xw = xsx[w];

    for (int i=tid;i<1536;i+=128){
        *(v8h*)(gruHi + i*8) = *(const v8h*)(gHiG + (size_t)i*8);
        *(v8h*)(gruLo + i*8) = *(const v8h*)(gLoG + (size_t)i*8);
    }
    __syncthreads();

    v8h w1h[2][2], w1l[2][2];
    #pragma unroll
    for (int T=0;T<2;++T){
        int n = col + 16*T;
        w1h[T][0] = ld8s  (Wl1 + (     quad*8)*32 + n, 32);
        w1h[T][1] = ld8s  (Wl1 + (32 + quad*8)*32 + n, 32);
        w1l[T][0] = ld8slo(Wl1 + (     quad*8)*32 + n, 32);
        w1l[T][1] = ld8slo(Wl1 + (32 + quad*8)*32 + n, 32);
    }
    float wi0[12], wi1[12], bsum[8], bn_i[4], bn_h[4];
    #pragma unroll
    for (int T=0;T<12;++T){
        int c = col + 16*T;
        wi0[T] = wih[c*2]; wi1[T] = wih[c*2+1];
    }
    #pragma unroll
    for (int T=0;T<8;++T) bsum[T] = bih[col+16*T] + bhh[col+16*T];
    #pragma unroll
    for (int T=0;T<4;++T){
        bn_i[T] = bih[128+col+16*T];
        bn_h[T] = bhh[128+col+16*T];
    }
    float w2[2][4], bl1v[2];
    #pragma unroll
    for (int T=0;T<2;++T){
        int i5 = col + 16*T;
        bl1v[T] = bl1[i5];
        #pragma unroll
        for (int j=0;j<4;++j) w2[T][j] = Wl2[i5*4+j];
    }
    float b2[4] = {bl2[0], bl2[1], bl2[2], bl2[3]};

    float zc[4][4];
    #pragma unroll
    for (int Tz=0;Tz<4;++Tz)
        #pragma unroll
        for (int r=0;r<4;++r){
            float v = z0ws[(size_t)(b0+quad*4+r)*64 + col + 16*Tz];
            zc[Tz][r] = v;
            _Float16 h = (_Float16)v;
            int o = (quad*4+r)*200 + col + 16*Tz;
            sw[o] = h; sw[o+64] = (_Float16)(v-(float)h);
        }

    int bi = best[0];
    float x0i, x1i;
    if (bi >= 0){
        v2h xv = *(const v2h*)(traj16 + (size_t)(b0+col)*64 + bi*8 + 2*quad);
        x0i = (float)xv[0]; x1i = (float)xv[1];
    } else { x0i = bs[2*quad]; x1i = bs[2*quad+1]; }
    xw[col*8 + 2*quad]   = x0i;
    xw[col*8 + 2*quad+1] = x1i;

    float y0[4]={0,0,0,0}, y1[4]={0,0,0,0};
    #pragma unroll
    for (int t=0;t<4;++t){
        v8h ah0 = *(const v8h*)(sw + col*200 +      quad*8);
        v8h ah1 = *(const v8h*)(sw + col*200 + 32 + quad*8);
        v8h al0 = *(const v8h*)(sw + col*200 + 64 + quad*8);
        v8h al1 = *(const v8h*)(sw + col*200 + 96 + quad*8);
        #pragma unroll
        for (int Tz=0;Tz<4;++Tz){
            v4f g3[3];
            #pragma unroll
            for (int gg=0; gg<3; ++gg){
                int tg = Tz + 4*gg;
                v8h h0 = *(const v8h*)(gruHi + (tg*2  )*512 + ln*8);
                v8h h1 = *(const v8h*)(gruHi + (tg*2+1)*512 + ln*8);
                v8h l0 = *(const v8h*)(gruLo + (tg*2  )*512 + ln*8);
                v8h l1 = *(const v8h*)(gruLo + (tg*2+1)*512 + ln*8);
                v4f acc = {0,0,0,0};
                acc = MFMA16(ah0, l0, acc);
                acc = MFMA16(ah1, l1, acc);
                acc = MFMA16(al0, h0, acc);
                acc = MFMA16(al1, h1, acc);
                acc = MFMA16(ah0, h0, acc);
                acc = MFMA16(ah1, h1, acc);
                g3[gg] = acc;
            }
            #pragma unroll
            for (int r=0;r<4;++r){
                float pr = g3[0][r] + wi0[Tz]*y0[r]   + wi1[Tz]*y1[r]   + bsum[Tz];
                float pu = g3[1][r] + wi0[Tz+4]*y0[r] + wi1[Tz+4]*y1[r] + bsum[Tz+4];
                float gh = g3[2][r] + bn_h[Tz];
                float gi = wi0[Tz+8]*y0[r] + wi1[Tz+8]*y1[r] + bn_i[Tz];
                float R = fsigm(pr), U = fsigm(pu);
                float N = ftanh(gi + R*gh);
                zc[Tz][r] = (1.f-U)*N + U*zc[Tz][r];
            }
        }
        #pragma unroll
        for (int Tz=0;Tz<4;++Tz)
            #pragma unroll
            for (int r=0;r<4;++r){
                float v = zc[Tz][r];
                _Float16 h = (_Float16)v;
                int o = (quad*4+r)*200 + col + 16*Tz;
                sw[o] = h; sw[o+64] = (_Float16)(v-(float)h);
            }
        v8h bh0 = *(const v8h*)(sw + col*200 +      quad*8);
        v8h bh1 = *(const v8h*)(sw + col*200 + 32 + quad*8);
        v8h bl0 = *(const v8h*)(sw + col*200 + 64 + quad*8);
        v8h blf = *(const v8h*)(sw + col*200 + 96 + quad*8);
        float aaf[2][4];
        #pragma unroll
        for (int T=0;T<2;++T){
            v4f acc = {0.f,0.f,0.f,0.f};
            acc = MFMA16(bh0, w1l[T][0], acc);
            acc = MFMA16(bh1, w1l[T][1], acc);
            acc = MFMA16(bl0, w1h[T][0], acc);
            acc = MFMA16(blf, w1h[T][1], acc);
            acc = MFMA16(bh0, w1h[T][0], acc);
            acc = MFMA16(bh1, w1h[T][1], acc);
            #pragma unroll
            for (int r=0;r<4;++r) aaf[T][r] = fmaxf(acc[r] + bl1v[T], 0.f);
        }
        #pragma unroll
        for (int r=0;r<4;++r){
            float q0 = aaf[0][r]*w2[0][0] + aaf[1][r]*w2[1][0];
            float q1 = aaf[0][r]*w2[0][1] + aaf[1][r]*w2[1][1];
            float q2 = aaf[0][r]*w2[0][2] + aaf[1][r]*w2[1][2];
            float q3 = aaf[0][r]*w2[0][3] + aaf[1][r]*w2[1][3];
            #pragma unroll
            for (int m=1;m<16;m<<=1){
                q0 += __shfl_xor(q0,m); q1 += __shfl_xor(q1,m);
                q2 += __shfl_xor(q2,m); q3 += __shfl_xor(q3,m);
            }
            float c0 = q0 + b2[0], c1 = q1 + b2[1];
            float s0 = fsp(q2 + b2[2]) + 0.001f;
            float s1 = fsp(q3 + b2[3]) + 0.001f;
            float xv0 = xw[(quad*4+r)*8 + 2*t];
            float xv1 = xw[(quad*4+r)*8 + 2*t + 1];
            y0[r] += c0 + s0*xv0;
            y1[r] += c1 + s1*xv1;
            if (col == 0){
                v2f o; o[0]=y0[r]; o[1]=y1[r];
                *(v2f*)(outp + (size_t)(b0+quad*4+r)*8 + 2*t) = o;
            }
        }
    }
}

// ---------------------------------------------------------------------------
extern "C" void kernel_launch(void* const* d_in, const int* in_sizes, int n_in,
                              void* d_out, int out_size, void* d_ws, size_t ws_size,
                              hipStream_t stream)
{
    const float* visual = (const float*)d_in[0];
    const float* vel    = (const float*)d_in[1];
    const float* tl     = (const float*)d_in[2];
    const float* tls    = (const float*)d_in[3];
    const float* goal   = (const float*)d_in[4];
    const float* bs     = (const float*)d_in[5];
    const float* Wm1    = (const float*)d_in[6];
    const float* bm1    = (const float*)d_in[7];
    const float* Wm2    = (const float*)d_in[8];
    const float* bm2    = (const float*)d_in[9];
    const float* Wm3    = (const float*)d_in[10];
    const float* bm3    = (const float*)d_in[11];
    const float* wih    = (const float*)d_in[12];
    const float* whh    = (const float*)d_in[13];
    const float* bih    = (const float*)d_in[14];
    const float* bhh    = (const float*)d_in[15];
    const float* Wl1    = (const float*)d_in[16];
    const float* bl1    = (const float*)d_in[17];
    const float* Wl2    = (const float*)d_in[18];
    const float* bl2    = (const float*)d_in[19];
    const int*   nsp    = (const int*)d_in[20];

    // ws layout (12.08 MiB total — inside R5/R6's proven 14.03 MiB footprint)
    float*    z0ws   = (float*)d_ws;                          // B*64 f32   (4 MiB)
    _Float16* traj16 = (_Float16*)(z0ws + (size_t)BATCH*64);  // B*64 f16   (2 MiB)
    float*    parts  = (float*)(traj16 + (size_t)BATCH*64);   // 8*1024 f32 (32 KB)
    int*      best   = (int*)(parts + NSMAX*1024);            // 4 ints
    _Float16* ckpt   = (_Float16*)(best + 4);                 // 3*B*64 f16 (6 MiB)
    _Float16* gHiG   = ckpt + (size_t)3*BATCH*64;             // 12288 f16  (24 KB)
    _Float16* gLoG   = gHiG + 12288;                          // 12288 f16
    _Float16* gTG    = gLoG + 12288;                          // 12288 f16

    k_prep<<<6, 256, 0, stream>>>(whh, gHiG, gLoG, gTG);

    k_mlp<<<BATCH/8, 512, 0, stream>>>(visual, vel, tl, tls,
        Wm1, bm1, Wm2, bm2, Wm3, bm3, z0ws);

    k_adam<<<BATCH/32, 128, 0, stream>>>(goal, bs,
        wih, whh, bih, bhh, Wl1, bl1, Wl2, bl2,
        nsp, z0ws, traj16, parts, ckpt, gHiG, gLoG, gTG);

    k_pick<<<1, 64, 0, stream>>>(nsp, parts, best);

    k_final<<<BATCH/32, 128, 0, stream>>>(bs,
        wih, whh, bih, bhh, Wl1, bl1, Wl2, bl2,
        z0ws, traj16, best, gHiG, gLoG, (float*)d_out);
}

// Round 10
// 695.434 us; speedup vs baseline: 2.6403x; 1.0901x over previous
//
#include <hip/hip_runtime.h>
#include <math.h>

#define BATCH 16384
#define NSMAX 8
#define LOG2PI_F 1.8378770664093453f
#define LOG4_F 1.3862943611198906f

typedef _Float16 v8h __attribute__((ext_vector_type(8)));
typedef _Float16 v2h __attribute__((ext_vector_type(2)));
typedef float    v4f __attribute__((ext_vector_type(4)));
typedef float    v2f __attribute__((ext_vector_type(2)));

#define MFMA16(A,B,C) __builtin_amdgcn_mfma_f32_16x16x32_f16(A,B,C,0,0,0)

__device__ __forceinline__ float bcast(float v, int l) {
    return __uint_as_float(__builtin_amdgcn_readlane(__float_as_uint(v), (unsigned)l));
}
__device__ __forceinline__ float fsigm(float v){ return 1.f/(1.f + __expf(-v)); }
__device__ __forceinline__ float ftanh(float v){ return 1.f - 2.f/(__expf(2.f*v)+1.f); }
__device__ __forceinline__ float fsp(float v){ return fmaxf(v,0.f) + __logf(1.f + __expf(-fabsf(v))); }

__device__ __forceinline__ v8h ld8(const float* p){
    v4f a = *(const v4f*)p; v4f b = *(const v4f*)(p+4);
    v8h r;
    r[0]=(_Float16)a[0]; r[1]=(_Float16)a[1]; r[2]=(_Float16)a[2]; r[3]=(_Float16)a[3];
    r[4]=(_Float16)b[0]; r[5]=(_Float16)b[1]; r[6]=(_Float16)b[2]; r[7]=(_Float16)b[3];
    return r;
}
__device__ __forceinline__ v8h ld8lo(const float* p){
    v4f a = *(const v4f*)p; v4f b = *(const v4f*)(p+4);
    v8h r;
    #pragma unroll
    for (int j=0;j<4;++j){ _Float16 h=(_Float16)a[j]; r[j]=(_Float16)(a[j]-(float)h); }
    #pragma unroll
    for (int j=0;j<4;++j){ _Float16 h=(_Float16)b[j]; r[4+j]=(_Float16)(b[j]-(float)h); }
    return r;
}
__device__ __forceinline__ v8h ld8s(const float* p, int stride){
    v8h r;
    #pragma unroll
    for (int j=0;j<8;++j) r[j] = (_Float16)p[j*stride];
    return r;
}
__device__ __forceinline__ v8h ld8slo(const float* p, int stride){
    v8h r;
    #pragma unroll
    for (int j=0;j<8;++j){ float v=p[j*stride]; _Float16 h=(_Float16)v; r[j]=(_Float16)(v-(float)h); }
    return r;
}

// ---------------------------------------------------------------------------
// K-1: pre-convert whh into fp16 frag images (gHi/gLo/gT) in d_ws.
// ---------------------------------------------------------------------------
__global__ void k_prep(const float* __restrict__ whh,
                       _Float16* __restrict__ gHiG,
                       _Float16* __restrict__ gLoG,
                       _Float16* __restrict__ gTG)
{
    int i = blockIdx.x*256 + threadIdx.x;
    if (i < 1536){
        int f = i>>6, l = i&63, lc = l&15, lq = l>>4;
        int T = f>>1, K = f&1;
        *(v8h*)(gHiG + (size_t)f*512 + l*8) = ld8  (whh + (lc+16*T)*64 + 32*K + lq*8);
        *(v8h*)(gLoG + (size_t)f*512 + l*8) = ld8lo(whh + (lc+16*T)*64 + 32*K + lq*8);
        int Tz = f/6, kc = f - Tz*6;
        *(v8h*)(gTG  + (size_t)f*512 + l*8) = ld8s(whh + (kc*32+lq*8)*64 + lc + 16*Tz, 64);
    }
}

// ---------------------------------------------------------------------------
// K0: MLP -> z0 (fp32 scalar, proven)
// ---------------------------------------------------------------------------
__global__ __launch_bounds__(512) void k_mlp(
    const float* __restrict__ visual, const float* __restrict__ vel,
    const float* __restrict__ tl, const float* __restrict__ tls,
    const float* __restrict__ Wm1, const float* __restrict__ bm1,
    const float* __restrict__ Wm2, const float* __restrict__ bm2,
    const float* __restrict__ Wm3, const float* __restrict__ bm3,
    float* __restrict__ z0ws)
{
    __shared__ float smem[9600];
    const int tid  = threadIdx.x;
    const int lane = tid & 63;
    const int w    = tid >> 6;
    const int b    = blockIdx.x * 8 + w;
    for (int i = tid; i < 8512; i += 512) smem[i] = Wm1[i];
    float* sfeat = smem + 8512 + w * 136;
    sfeat[lane]      = visual[b*128 + lane];
    sfeat[64 + lane] = visual[b*128 + 64 + lane];
    if (lane < 3)  sfeat[128 + lane] = vel[b*3 + lane];
    if (lane == 3) sfeat[131] = tl[b];
    if (lane == 4) sfeat[132] = tls[b];
    __syncthreads();
    float acc = bm1[lane];
    for (int f = 0; f < 133; ++f) acc = fmaf(smem[f*64 + lane], sfeat[f], acc);
    float z1 = fmaxf(acc, 0.f);
    __syncthreads();
    for (int i = tid; i < 4096; i += 512) smem[i] = Wm2[i];
    __syncthreads();
    acc = bm2[lane];
    #pragma unroll 8
    for (int kk = 0; kk < 64; ++kk) acc = fmaf(smem[kk*64 + lane], bcast(z1, kk), acc);
    float z2 = fmaxf(acc, 0.f);
    __syncthreads();
    for (int i = tid; i < 4096; i += 512) smem[i] = Wm3[i];
    __syncthreads();
    acc = bm3[lane];
    #pragma unroll 8
    for (int kk = 0; kk < 64; ++kk) acc = fmaf(smem[kk*64 + lane], bcast(z2, kk), acc);
    z0ws[(size_t)b*64 + lane] = fmaxf(acc, 0.f);
}

// ---------------------------------------------------------------------------
// K1: MFMA flow — R9 base + (a) Wl1-family frags to LDS (w1f/awf),
// (b) zcp/znew/zprev arrays eliminated (fwd in-place zc; bwd stages z_t to
// +64 region, z_{t-1} stays in cols 0..63 and is re-read from stage).
// Numerics bit-identical to R9.
// ---------------------------------------------------------------------------
__global__ __launch_bounds__(128, 1) void k_adam(
    const float* __restrict__ goal, const float* __restrict__ bs,
    const float* __restrict__ wih, const float* __restrict__ whh,
    const float* __restrict__ bih, const float* __restrict__ bhh,
    const float* __restrict__ Wl1, const float* __restrict__ bl1,
    const float* __restrict__ Wl2, const float* __restrict__ bl2,
    const int*  __restrict__ nsp, const float* __restrict__ z0ws,
    _Float16* __restrict__ traj16, float* __restrict__ parts,
    _Float16* __restrict__ ckpt,
    const _Float16* __restrict__ gHiG, const _Float16* __restrict__ gLoG,
    const _Float16* __restrict__ gTG)
{
    __shared__ _Float16 gruHi[12288];     // hi(whh) frag-ordered, 24KB
    __shared__ _Float16 regB [12288];     // swap: gruLo (fwd) / whhT (bwd), 24KB
    __shared__ _Float16 w1f[4096];        // Wl1 frags f=T*4+K*2+hl, 8KB
    __shared__ _Float16 awf[2048];        // bwd dz B frags f=Tz, 4KB
    __shared__ _Float16 stageL[2][3200];  // per-wave stage, stride 200 halfs
    __shared__ float    xsx[2][256];      // per-wave x / xbar

    const int tid  = threadIdx.x;
    const int w    = tid >> 6;
    const int ln   = tid & 63;
    const int col  = ln & 15;
    const int quad = ln >> 4;
    const int b0   = blockIdx.x*32 + w*16;
    _Float16* sw = stageL[w];
    float*    xw = xsx[w];

    // one-time LDS init (covered by first s-loop barrier)
    for (int i=tid;i<1536;i+=128)
        *(v8h*)(gruHi + i*8) = *(const v8h*)(gHiG + (size_t)i*8);
    for (int i = tid; i < 8*64; i += 128){
        int f=i>>6, l=i&63, lc=l&15, lq=l>>4;
        int T=f>>2, K=(f>>1)&1, hl=f&1;
        const float* p = Wl1 + (32*K + lq*8)*32 + (lc+16*T);
        *(v8h*)(w1f + f*512 + l*8) = hl ? ld8slo(p,32) : ld8s(p,32);
    }
    for (int i = tid; i < 4*64; i += 128){
        int f=i>>6, l=i&63, lc=l&15, lq=l>>4;
        *(v8h*)(awf + f*512 + l*8) = ld8(Wl1 + (lc+16*f)*32 + lq*8);
    }

    // ---- scalar params in registers (R9-exact set) ----
    float wi0[12], wi1[12];
    #pragma unroll
    for (int T=0;T<12;++T){
        int c = col + 16*T;
        wi0[T] = wih[c*2]; wi1[T] = wih[c*2+1];
    }
    float bsum[8], bn_i[4], bn_h[4];
    #pragma unroll
    for (int T=0;T<8;++T) bsum[T] = bih[col+16*T] + bhh[col+16*T];
    #pragma unroll
    for (int T=0;T<4;++T){
        bn_i[T] = bih[128+col+16*T];
        bn_h[T] = bhh[128+col+16*T];
    }
    float w2[2][4], bl1v[2];
    #pragma unroll
    for (int T=0;T<2;++T){
        int i5 = col + 16*T;
        bl1v[T] = bl1[i5];
        #pragma unroll
        for (int j=0;j<4;++j) w2[T][j] = Wl2[i5*4+j];
    }
    float b2[4] = {bl2[0], bl2[1], bl2[2], bl2[3]};

    float xa0 = bs[2*quad], xa1 = bs[2*quad+1];
    xw[col*16 + 2*quad]   = xa0;
    xw[col*16 + 2*quad+1] = xa1;
    float am0=0,am1=0,av0=0,av1=0,pb1=1.f,pb2=1.f;

    int ns = *nsp; if (ns > NSMAX) ns = NSMAX;

    _Float16 rg[4][4], ug[4][4], ngv[4][4];
    float ghs[4][4], aa[2][4];
    float s0v[4], s1v[4], c0v[4], c1v[4];
    float zc[4][4];

    // GRU cell + heads.
    // split=true (fwd): 6-term, zc updated in place, stages hi(0..63)+lo(64..127).
    // split=false (bwd): 2-term; z_{t-1} read from stage cols 0..63 (left intact);
    //                    z_t staged f16 to cols 64..127; head reads from +64.
    auto cell = [&](bool split, const float (&yp0)[4], const float (&yp1)[4]){
        v8h ah0 = *(const v8h*)(sw + col*200 +      quad*8);
        v8h ah1 = *(const v8h*)(sw + col*200 + 32 + quad*8);
        v8h al0, al1;
        if (split){
            al0 = *(const v8h*)(sw + col*200 + 64 + quad*8);
            al1 = *(const v8h*)(sw + col*200 + 96 + quad*8);
        }
        #pragma unroll
        for (int Tz=0;Tz<4;++Tz){
            v4f g3[3];
            #pragma unroll
            for (int gg=0; gg<3; ++gg){
                int tg = Tz + 4*gg;
                v8h h0 = *(const v8h*)(gruHi + (tg*2  )*512 + ln*8);
                v8h h1 = *(const v8h*)(gruHi + (tg*2+1)*512 + ln*8);
                v4f acc = {0,0,0,0};
                if (split){
                    v8h l0 = *(const v8h*)(regB + (tg*2  )*512 + ln*8);
                    v8h l1 = *(const v8h*)(regB + (tg*2+1)*512 + ln*8);
                    acc = MFMA16(ah0, l0, acc);
                    acc = MFMA16(ah1, l1, acc);
                    acc = MFMA16(al0, h0, acc);
                    acc = MFMA16(al1, h1, acc);
                }
                acc = MFMA16(ah0, h0, acc);
                acc = MFMA16(ah1, h1, acc);
                g3[gg] = acc;
            }
            #pragma unroll
            for (int r=0;r<4;++r){
                float pr = g3[0][r] + wi0[Tz]*yp0[r]   + wi1[Tz]*yp1[r]   + bsum[Tz];
                float pu = g3[1][r] + wi0[Tz+4]*yp0[r] + wi1[Tz+4]*yp1[r] + bsum[Tz+4];
                float gh = g3[2][r] + bn_h[Tz];
                float gi = wi0[Tz+8]*yp0[r] + wi1[Tz+8]*yp1[r] + bn_i[Tz];
                float R = fsigm(pr), U = fsigm(pu);
                float N = ftanh(gi + R*gh);
                if (split){
                    zc[Tz][r] = (1.f-U)*N + U*zc[Tz][r];
                } else {
                    rg[Tz][r]=(_Float16)R; ug[Tz][r]=(_Float16)U;
                    ngv[Tz][r]=(_Float16)N; ghs[Tz][r]=gh;
                    int o = (quad*4+r)*200 + col + 16*Tz;
                    float zp = (float)sw[o];            // z_{t-1} (cols 0..63 intact)
                    sw[o + 64] = (_Float16)((1.f-U)*N + U*zp);   // z_t -> +64
                }
            }
        }
        if (split){
            #pragma unroll
            for (int Tz=0;Tz<4;++Tz)
                #pragma unroll
                for (int r=0;r<4;++r){
                    float v = zc[Tz][r];
                    _Float16 h = (_Float16)v;
                    int o = (quad*4+r)*200 + col + 16*Tz;
                    sw[o] = h; sw[o+64] = (_Float16)(v-(float)h);
                }
        }
        const int hb = split ? 0 : 64;
        v8h bh0 = *(const v8h*)(sw + col*200 + hb +      quad*8);
        v8h bh1 = *(const v8h*)(sw + col*200 + hb + 32 + quad*8);
        v8h bl0, blf;
        if (split){
            bl0 = *(const v8h*)(sw + col*200 + 64 + quad*8);
            blf = *(const v8h*)(sw + col*200 + 96 + quad*8);
        }
        #pragma unroll
        for (int T=0;T<2;++T){
            v8h w1l0 = *(const v8h*)(w1f + (T*4+1)*512 + ln*8);
            v8h w1l1 = *(const v8h*)(w1f + (T*4+3)*512 + ln*8);
            v8h w1h0 = *(const v8h*)(w1f + (T*4+0)*512 + ln*8);
            v8h w1h1 = *(const v8h*)(w1f + (T*4+2)*512 + ln*8);
            v4f acc = {0.f,0.f,0.f,0.f};
            acc = MFMA16(bh0, w1l0, acc);
            acc = MFMA16(bh1, w1l1, acc);
            if (split){
                acc = MFMA16(bl0, w1h0, acc);
                acc = MFMA16(blf, w1h1, acc);
            }
            acc = MFMA16(bh0, w1h0, acc);
            acc = MFMA16(bh1, w1h1, acc);
            #pragma unroll
            for (int r=0;r<4;++r) aa[T][r] = fmaxf(acc[r] + bl1v[T], 0.f);
        }
        #pragma unroll
        for (int r=0;r<4;++r){
            float q2 = aa[0][r]*w2[0][2] + aa[1][r]*w2[1][2];
            float q3 = aa[0][r]*w2[0][3] + aa[1][r]*w2[1][3];
            float q0 = 0.f, q1 = 0.f;
            if (split){
                q0 = aa[0][r]*w2[0][0] + aa[1][r]*w2[1][0];
                q1 = aa[0][r]*w2[0][1] + aa[1][r]*w2[1][1];
            }
            #pragma unroll
            for (int m=1;m<16;m<<=1){
                q2 += __shfl_xor(q2,m); q3 += __shfl_xor(q3,m);
                if (split){ q0 += __shfl_xor(q0,m); q1 += __shfl_xor(q1,m); }
            }
            if (split){ c0v[r] = q0 + b2[0]; c1v[r] = q1 + b2[1]; }
            s0v[r] = fsp(q2 + b2[2]) + 0.001f;
            s1v[r] = fsp(q3 + b2[3]) + 0.001f;
        }
    };

    const int crow = ln >> 2;
    const int ccol = (ln & 3) * 16;

    for (int s=0; s<ns; ++s){
        __syncthreads();                 // prior-phase regB reads (and init) done
        for (int i=tid;i<1536;i+=128)    // regB = gruLo (coalesced copy)
            *(v8h*)(regB + i*8) = *(const v8h*)(gLoG + (size_t)i*8);
        __syncthreads();
        // reset z to z0 (stage split)
        #pragma unroll
        for (int Tz=0;Tz<4;++Tz)
            #pragma unroll
            for (int r=0;r<4;++r){
                float v = z0ws[(size_t)(b0+quad*4+r)*64 + col + 16*Tz];
                zc[Tz][r] = v;
                _Float16 h = (_Float16)v;
                int o = (quad*4+r)*200 + col + 16*Tz;
                sw[o] = h; sw[o+64] = (_Float16)(v-(float)h);
            }
        // ---------- forward ----------
        float y0[4]={0,0,0,0}, y1[4]={0,0,0,0};
        float sumls[4]={0,0,0,0}, sumx2[4]={0,0,0,0};
        #pragma unroll
        for (int t=0;t<4;++t){
            cell(true, y0, y1);
            #pragma unroll
            for (int r=0;r<4;++r){
                v2f xv = *(const v2f*)(&xw[(quad*4+r)*16 + 2*t]);
                sumx2[r] += xv[0]*xv[0] + xv[1]*xv[1];
                y0[r] += c0v[r] + s0v[r]*xv[0];
                y1[r] += c1v[r] + s1v[r]*xv[1];
                int o = (quad*4+r)*200 + 192 + 2*t;
                sw[o] = (_Float16)y0[r]; sw[o+1] = (_Float16)y1[r];
                sumls[r] += __logf(s0v[r]) + __logf(s1v[r]);
            }
            if (t<3){
                v8h z1 = *(const v8h*)(sw + crow*200 + ccol);
                v8h z2 = *(const v8h*)(sw + crow*200 + ccol + 8);
                _Float16* gp = ckpt + ((size_t)t*BATCH + (b0+crow))*64 + ccol;
                *(v8h*)gp = z1; *(v8h*)(gp+8) = z2;
            }
        }
        // ---------- loss + y-grad ----------
        float cel[4], yb0[4], yb1[4];
        #pragma unroll
        for (int r=0;r<4;++r){
            const float* gpt = goal + (size_t)(b0+quad*4+r)*8;
            v4f ga = *(const v4f*)gpt; v4f gb = *(const v4f*)(gpt+4);
            float c0_ = -0.5f*((y0[r]-ga[0])*(y0[r]-ga[0]) + (y1[r]-ga[1])*(y1[r]-ga[1])) - LOG2PI_F;
            float c1_ = -0.5f*((y0[r]-ga[2])*(y0[r]-ga[2]) + (y1[r]-ga[3])*(y1[r]-ga[3])) - LOG2PI_F;
            float c2_ = -0.5f*((y0[r]-gb[0])*(y0[r]-gb[0]) + (y1[r]-gb[1])*(y1[r]-gb[1])) - LOG2PI_F;
            float c3_ = -0.5f*((y0[r]-gb[2])*(y0[r]-gb[2]) + (y1[r]-gb[3])*(y1[r]-gb[3])) - LOG2PI_F;
            float mx = fmaxf(fmaxf(c0_,c1_), fmaxf(c2_,c3_));
            float e0 = __expf(c0_-mx), e1 = __expf(c1_-mx), e2 = __expf(c2_-mx), e3 = __expf(c3_-mx);
            float se = e0+e1+e2+e3;
            float lp = mx + __logf(se) - LOG4_F;
            cel[r] = -0.5f*sumx2[r] - 4.f*LOG2PI_F - sumls[r] + lp;
            float inv = 1.f/se;
            yb0[r] = inv*(e0*(ga[0]-y0[r]) + e1*(ga[2]-y0[r]) + e2*(gb[0]-y0[r]) + e3*(gb[2]-y0[r]));
            yb1[r] = inv*(e0*(ga[1]-y1[r]) + e1*(ga[3]-y1[r]) + e2*(gb[1]-y1[r]) + e3*(gb[3]-y1[r]));
        }
        float tsum = cel[0]+cel[1]+cel[2]+cel[3];
        tsum += __shfl_xor(tsum,16); tsum += __shfl_xor(tsum,32);
        if (ln==0) parts[s*1024 + blockIdx.x*2 + w] = tsum;

        __syncthreads();                 // fwd regB reads done
        for (int i=tid;i<1536;i+=128)    // regB = whhT (coalesced copy)
            *(v8h*)(regB + i*8) = *(const v8h*)(gTG + (size_t)i*8);
        __syncthreads();

        // ---------- backward ----------
        float zbN[4][4];
        #pragma unroll
        for (int Tz=0;Tz<4;++Tz){ zbN[Tz][0]=0;zbN[Tz][1]=0;zbN[Tz][2]=0;zbN[Tz][3]=0; }
        #pragma unroll
        for (int tt=0; tt<4; ++tt){
            const int t = 3-tt;
            if (t > 0){
                const _Float16* gp = ckpt + ((size_t)(t-1)*BATCH + (b0+crow))*64 + ccol;
                v8h z1 = *(const v8h*)gp; v8h z2 = *(const v8h*)(gp+8);
                *(v8h*)(sw + crow*200 + ccol)     = z1;
                *(v8h*)(sw + crow*200 + ccol + 8) = z2;
            } else {
                #pragma unroll
                for (int Tz=0;Tz<4;++Tz)
                    #pragma unroll
                    for (int r=0;r<4;++r)
                        sw[(quad*4+r)*200 + col + 16*Tz] =
                            (_Float16)z0ws[(size_t)(b0+quad*4+r)*64 + col + 16*Tz];
            }
            float yp0[4], yp1[4];
            #pragma unroll
            for (int r=0;r<4;++r){
                if (t==0){ yp0[r]=0.f; yp1[r]=0.f; }
                else {
                    int o = (quad*4+r)*200 + 192 + 2*(t-1);
                    yp0[r] = (float)sw[o]; yp1[r] = (float)sw[o+1];
                }
            }
            cell(false, yp0, yp1);

            float l2[4], l3[4];
            #pragma unroll
            for (int r=0;r<4;++r){
                v2f xv = *(const v2f*)(&xw[(quad*4+r)*16 + 2*t]);
                float sb0 = yb0[r]*xv[0] - 1.f/s0v[r];
                float sb1 = yb1[r]*xv[1] - 1.f/s1v[r];
                float sg0 = 1.f - __expf(-(s0v[r]-0.001f));
                float sg1 = 1.f - __expf(-(s1v[r]-0.001f));
                l2[r] = sb0*sg0; l3[r] = sb1*sg1;
                v2f xb; xb[0] = yb0[r]*s0v[r] - xv[0]; xb[1] = yb1[r]*s1v[r] - xv[1];
                *(v2f*)(&xw[(quad*4+r)*16 + 8 + 2*t]) = xb;
            }
            #pragma unroll
            for (int T=0;T<2;++T)
                #pragma unroll
                for (int r=0;r<4;++r){
                    float ab = w2[T][0]*yb0[r] + w2[T][1]*yb1[r] + w2[T][2]*l2[r] + w2[T][3]*l3[r];
                    ab = (aa[T][r] > 0.f) ? ab : 0.f;
                    sw[(quad*4+r)*200 + 128 + col + 16*T] = (_Float16)ab;
                }
            v8h a_ab = *(const v8h*)(sw + col*200 + 128 + quad*8);
            float dzt[4][4];
            #pragma unroll
            for (int Tz=0;Tz<4;++Tz){
                v8h bw1 = *(const v8h*)(awf + Tz*512 + ln*8);
                v4f acc = { zbN[Tz][0], zbN[Tz][1], zbN[Tz][2], zbN[Tz][3] };
                acc = MFMA16(a_ab, bw1, acc);
                #pragma unroll
                for (int r=0;r<4;++r) dzt[Tz][r] = acc[r];
            }
            float px0[4] = {0,0,0,0}, px1[4] = {0,0,0,0};
            #pragma unroll
            for (int Tz=0;Tz<4;++Tz)
                #pragma unroll
                for (int r=0;r<4;++r){
                    float R = (float)rg[Tz][r];
                    float N = (float)ngv[Tz][r];
                    float U = (float)ug[Tz][r];
                    float GH= ghs[Tz][r];
                    int o = (quad*4+r)*200 + col + 16*Tz;
                    float zp = (float)sw[o];         // z_{t-1} (read before dr write)
                    float nb = dzt[Tz][r]*(1.f-U);
                    float dn = nb*(1.f-N*N);
                    float gnb = dn*R;
                    float rb  = dn*GH;
                    float dr  = rb*R*(1.f-R);
                    float du  = dzt[Tz][r]*(zp-N)*U*(1.f-U);
                    sw[o]       = (_Float16)dr;
                    sw[o + 64]  = (_Float16)du;
                    sw[o + 128] = (_Float16)gnb;
                    px0[r] += dr*wi0[Tz] + du*wi0[Tz+4] + dn*wi0[Tz+8];
                    px1[r] += dr*wi1[Tz] + du*wi1[Tz+4] + dn*wi1[Tz+8];
                }
            v8h adg[6];
            #pragma unroll
            for (int kc=0;kc<6;++kc)
                adg[kc] = *(const v8h*)(sw + col*200 + kc*32 + quad*8);
            #pragma unroll
            for (int Tz=0;Tz<4;++Tz){
                v4f acc;
                #pragma unroll
                for (int r=0;r<4;++r) acc[r] = dzt[Tz][r]*(float)ug[Tz][r];
                #pragma unroll
                for (int kc=0;kc<6;++kc){
                    v8h bwt = *(const v8h*)(regB + (Tz*6+kc)*512 + ln*8);
                    acc = MFMA16(adg[kc], bwt, acc);
                }
                #pragma unroll
                for (int r=0;r<4;++r) zbN[Tz][r] = acc[r];
            }
            #pragma unroll
            for (int r=0;r<4;++r){
                float p0 = px0[r], p1 = px1[r];
                #pragma unroll
                for (int m=1;m<16;m<<=1){ p0 += __shfl_xor(p0,m); p1 += __shfl_xor(p1,m); }
                yb0[r] += p0; yb1[r] += p1;
            }
        }
        // ---------- Adam ----------
        v2f xb = *(const v2f*)(&xw[col*16 + 8 + 2*quad]);
        float g0 = xb[0] * (-1.f/16384.f), g1 = xb[1] * (-1.f/16384.f);
        am0 = 0.9f*am0 + 0.1f*g0;        am1 = 0.9f*am1 + 0.1f*g1;
        av0 = 0.999f*av0 + 0.001f*g0*g0; av1 = 0.999f*av1 + 0.001f*g1*g1;
        pb1 *= 0.9f; pb2 *= 0.999f;
        float ic1 = 1.f/(1.f-pb1), ic2 = 1.f/(1.f-pb2);
        xa0 -= 0.1f*(am0*ic1)/(sqrtf(av0*ic2) + 1e-8f);
        xa1 -= 0.1f*(am1*ic1)/(sqrtf(av1*ic2) + 1e-8f);
        xw[col*16 + 2*quad]   = xa0;
        xw[col*16 + 2*quad+1] = xa1;
        v2h tv; tv[0]=(_Float16)xa0; tv[1]=(_Float16)xa1;
        *(v2h*)(traj16 + (size_t)(b0+col)*64 + s*8 + 2*quad) = tv;
    }
}

// ---------------------------------------------------------------------------
// K2: pick best step
// ---------------------------------------------------------------------------
__global__ void k_pick(const int* __restrict__ nsp,
                       const float* __restrict__ parts, int* __restrict__ best)
{
    int ln = threadIdx.x & 63;
    int ns = *nsp; if (ns > NSMAX) ns = NSMAX;
    float losses[NSMAX];
    for (int s=0;s<NSMAX;++s){
        float acc = 0.f;
        if (s < ns){
            for (int i=ln;i<1024;i+=64) acc += parts[s*1024+i];
            #pragma unroll
            for (int m=1;m<64;m<<=1) acc += __shfl_xor(acc,m);
        }
        losses[s] = -acc * (1.f/16384.f);
    }
    if (ln==0 && blockIdx.x==0){
        float lb = 1000.f; int bi = -1;
        for (int s=0;s<ns;++s) if (losses[s] < lb){ lb = losses[s]; bi = s; }
        best[0] = bi;
    }
}

// ---------------------------------------------------------------------------
// K3: final forward from x_best — R9-verbatim
// ---------------------------------------------------------------------------
__global__ __launch_bounds__(128, 1) void k_final(
    const float* __restrict__ bs,
    const float* __restrict__ wih, const float* __restrict__ whh,
    const float* __restrict__ bih, const float* __restrict__ bhh,
    const float* __restrict__ Wl1, const float* __restrict__ bl1,
    const float* __restrict__ Wl2, const float* __restrict__ bl2,
    const float* __restrict__ z0ws, const _Float16* __restrict__ traj16,
    const int* __restrict__ best,
    const _Float16* __restrict__ gHiG, const _Float16* __restrict__ gLoG,
    float* __restrict__ outp)
{
    __shared__ _Float16 gruHi[12288];
    __shared__ _Float16 gruLo[12288];
    __shared__ _Float16 stageL[2][3200];
    __shared__ float    xsx[2][128];

    const int tid  = threadIdx.x;
    const int w    = tid >> 6;
    const int ln   = tid & 63;
    const int col  = ln & 15;
    const int quad = ln >> 4;
    const int b0   = blockIdx.x*32 + w*16;
    _Float16* sw = stageL[w];
    float*    xw = xsx[w];

    for (int i=tid;i<1536;i+=128){
        *(v8h*)(gruHi + i*8) = *(const v8h*)(gHiG + (size_t)i*8);
        *(v8h*)(gruLo + i*8) = *(const v8h*)(gLoG + (size_t)i*8);
    }
    __syncthreads();

    v8h w1h[2][2], w1l[2][2];
    #pragma unroll
    for (int T=0;T<2;++T){
        int n = col + 16*T;
        w1h[T][0] = ld8s  (Wl1 + (     quad*8)*32 + n, 32);
        w1h[T][1] = ld8s  (Wl1 + (32 + quad*8)*32 + n, 32);
        w1l[T][0] = ld8slo(Wl1 + (     quad*8)*32 + n, 32);
        w1l[T][1] = ld8slo(Wl1 + (32 + quad*8)*32 + n, 32);
    }
    float wi0[12], wi1[12], bsum[8], bn_i[4], bn_h[4];
    #pragma unroll
    for (int T=0;T<12;++T){
        int c = col + 16*T;
        wi0[T] = wih[c*2]; wi1[T] = wih[c*2+1];
    }
    #pragma unroll
    for (int T=0;T<8;++T) bsum[T] = bih[col+16*T] + bhh[col+16*T];
    #pragma unroll
    for (int T=0;T<4;++T){
        bn_i[T] = bih[128+col+16*T];
        bn_h[T] = bhh[128+col+16*T];
    }
    float w2[2][4], bl1v[2];
    #pragma unroll
    for (int T=0;T<2;++T){
        int i5 = col + 16*T;
        bl1v[T] = bl1[i5];
        #pragma unroll
        for (int j=0;j<4;++j) w2[T][j] = Wl2[i5*4+j];
    }
    float b2[4] = {bl2[0], bl2[1], bl2[2], bl2[3]};

    float zc[4][4];
    #pragma unroll
    for (int Tz=0;Tz<4;++Tz)
        #pragma unroll
        for (int r=0;r<4;++r){
            float v = z0ws[(size_t)(b0+quad*4+r)*64 + col + 16*Tz];
            zc[Tz][r] = v;
            _Float16 h = (_Float16)v;
            int o = (quad*4+r)*200 + col + 16*Tz;
            sw[o] = h; sw[o+64] = (_Float16)(v-(float)h);
        }

    int bi = best[0];
    float x0i, x1i;
    if (bi >= 0){
        v2h xv = *(const v2h*)(traj16 + (size_t)(b0+col)*64 + bi*8 + 2*quad);
        x0i = (float)xv[0]; x1i = (float)xv[1];
    } else { x0i = bs[2*quad]; x1i = bs[2*quad+1]; }
    xw[col*8 + 2*quad]   = x0i;
    xw[col*8 + 2*quad+1] = x1i;

    float y0[4]={0,0,0,0}, y1[4]={0,0,0,0};
    #pragma unroll
    for (int t=0;t<4;++t){
        v8h ah0 = *(const v8h*)(sw + col*200 +      quad*8);
        v8h ah1 = *(const v8h*)(sw + col*200 + 32 + quad*8);
        v8h al0 = *(const v8h*)(sw + col*200 + 64 + quad*8);
        v8h al1 = *(const v8h*)(sw + col*200 + 96 + quad*8);
        #pragma unroll
        for (int Tz=0;Tz<4;++Tz){
            v4f g3[3];
            #pragma unroll
            for (int gg=0; gg<3; ++gg){
                int tg = Tz + 4*gg;
                v8h h0 = *(const v8h*)(gruHi + (tg*2  )*512 + ln*8);
                v8h h1 = *(const v8h*)(gruHi + (tg*2+1)*512 + ln*8);
                v8h l0 = *(const v8h*)(gruLo + (tg*2  )*512 + ln*8);
                v8h l1 = *(const v8h*)(gruLo + (tg*2+1)*512 + ln*8);
                v4f acc = {0,0,0,0};
                acc = MFMA16(ah0, l0, acc);
                acc = MFMA16(ah1, l1, acc);
                acc = MFMA16(al0, h0, acc);
                acc = MFMA16(al1, h1, acc);
                acc = MFMA16(ah0, h0, acc);
                acc = MFMA16(ah1, h1, acc);
                g3[gg] = acc;
            }
            #pragma unroll
            for (int r=0;r<4;++r){
                float pr = g3[0][r] + wi0[Tz]*y0[r]   + wi1[Tz]*y1[r]   + bsum[Tz];
                float pu = g3[1][r] + wi0[Tz+4]*y0[r] + wi1[Tz+4]*y1[r] + bsum[Tz+4];
                float gh = g3[2][r] + bn_h[Tz];
                float gi = wi0[Tz+8]*y0[r] + wi1[Tz+8]*y1[r] + bn_i[Tz];
                float R = fsigm(pr), U = fsigm(pu);
                float N = ftanh(gi + R*gh);
                zc[Tz][r] = (1.f-U)*N + U*zc[Tz][r];
            }
        }
        #pragma unroll
        for (int Tz=0;Tz<4;++Tz)
            #pragma unroll
            for (int r=0;r<4;++r){
                float v = zc[Tz][r];
                _Float16 h = (_Float16)v;
                int o = (quad*4+r)*200 + col + 16*Tz;
                sw[o] = h; sw[o+64] = (_Float16)(v-(float)h);
            }
        v8h bh0 = *(const v8h*)(sw + col*200 +      quad*8);
        v8h bh1 = *(const v8h*)(sw + col*200 + 32 + quad*8);
        v8h bl0 = *(const v8h*)(sw + col*200 + 64 + quad*8);
        v8h blf = *(const v8h*)(sw + col*200 + 96 + quad*8);
        float aaf[2][4];
        #pragma unroll
        for (int T=0;T<2;++T){
            v4f acc = {0.f,0.f,0.f,0.f};
            acc = MFMA16(bh0, w1l[T][0], acc);
            acc = MFMA16(bh1, w1l[T][1], acc);
            acc = MFMA16(bl0, w1h[T][0], acc);
            acc = MFMA16(blf, w1h[T][1], acc);
            acc = MFMA16(bh0, w1h[T][0], acc);
            acc = MFMA16(bh1, w1h[T][1], acc);
            #pragma unroll
            for (int r=0;r<4;++r) aaf[T][r] = fmaxf(acc[r] + bl1v[T], 0.f);
        }
        #pragma unroll
        for (int r=0;r<4;++r){
            float q0 = aaf[0][r]*w2[0][0] + aaf[1][r]*w2[1][0];
            float q1 = aaf[0][r]*w2[0][1] + aaf[1][r]*w2[1][1];
            float q2 = aaf[0][r]*w2[0][2] + aaf[1][r]*w2[1][2];
            float q3 = aaf[0][r]*w2[0][3] + aaf[1][r]*w2[1][3];
            #pragma unroll
            for (int m=1;m<16;m<<=1){
                q0 += __shfl_xor(q0,m); q1 += __shfl_xor(q1,m);
                q2 += __shfl_xor(q2,m); q3 += __shfl_xor(q3,m);
            }
            float c0 = q0 + b2[0], c1 = q1 + b2[1];
            float s0 = fsp(q2 + b2[2]) + 0.001f;
            float s1 = fsp(q3 + b2[3]) + 0.001f;
            float xv0 = xw[(quad*4+r)*8 + 2*t];
            float xv1 = xw[(quad*4+r)*8 + 2*t + 1];
            y0[r] += c0 + s0*xv0;
            y1[r] += c1 + s1*xv1;
            if (col == 0){
                v2f o; o[0]=y0[r]; o[1]=y1[r];
                *(v2f*)(outp + (size_t)(b0+quad*4+r)*8 + 2*t) = o;
            }
        }
    }
}

// ---------------------------------------------------------------------------
extern "C" void kernel_launch(void* const* d_in, const int* in_sizes, int n_in,
                              void* d_out, int out_size, void* d_ws, size_t ws_size,
                              hipStream_t stream)
{
    const float* visual = (const float*)d_in[0];
    const float* vel    = (const float*)d_in[1];
    const float* tl     = (const float*)d_in[2];
    const float* tls    = (const float*)d_in[3];
    const float* goal   = (const float*)d_in[4];
    const float* bs     = (const float*)d_in[5];
    const float* Wm1    = (const float*)d_in[6];
    const float* bm1    = (const float*)d_in[7];
    const float* Wm2    = (const float*)d_in[8];
    const float* bm2    = (const float*)d_in[9];
    const float* Wm3    = (const float*)d_in[10];
    const float* bm3    = (const float*)d_in[11];
    const float* wih    = (const float*)d_in[12];
    const float* whh    = (const float*)d_in[13];
    const float* bih    = (const float*)d_in[14];
    const float* bhh    = (const float*)d_in[15];
    const float* Wl1    = (const float*)d_in[16];
    const float* bl1    = (const float*)d_in[17];
    const float* Wl2    = (const float*)d_in[18];
    const float* bl2    = (const float*)d_in[19];
    const int*   nsp    = (const int*)d_in[20];

    // ws layout (12.08 MiB total — within proven footprint)
    float*    z0ws   = (float*)d_ws;                          // B*64 f32   (4 MiB)
    _Float16* traj16 = (_Float16*)(z0ws + (size_t)BATCH*64);  // B*64 f16   (2 MiB)
    float*    parts  = (float*)(traj16 + (size_t)BATCH*64);   // 8*1024 f32 (32 KB)
    int*      best   = (int*)(parts + NSMAX*1024);            // 4 ints
    _Float16* ckpt   = (_Float16*)(best + 4);                 // 3*B*64 f16 (6 MiB)
    _Float16* gHiG   = ckpt + (size_t)3*BATCH*64;             // 12288 f16
    _Float16* gLoG   = gHiG + 12288;                          // 12288 f16
    _Float16* gTG    = gLoG + 12288;                          // 12288 f16

    k_prep<<<6, 256, 0, stream>>>(whh, gHiG, gLoG, gTG);

    k_mlp<<<BATCH/8, 512, 0, stream>>>(visual, vel, tl, tls,
        Wm1, bm1, Wm2, bm2, Wm3, bm3, z0ws);

    k_adam<<<BATCH/32, 128, 0, stream>>>(goal, bs,
        wih, whh, bih, bhh, Wl1, bl1, Wl2, bl2,
        nsp, z0ws, traj16, parts, ckpt, gHiG, gLoG, gTG);

    k_pick<<<1, 64, 0, stream>>>(nsp, parts, best);

    k_final<<<BATCH/32, 128, 0, stream>>>(bs,
        wih, whh, bih, bhh, Wl1, bl1, Wl2, bl2,
        z0ws, traj16, best, gHiG, gLoG, (float*)d_out);
}